// Round 1
// baseline (4521.769 us; speedup 1.0000x reference)
//
#include <hip/hip_runtime.h>

#define Nn   50000
#define Ee   800000
#define INC  256
#define HIDd 128
#define RR   8
#define BB   4
#define LL   3
#define RN   (RR * Nn)   // 400000

static inline size_t align256(size_t x) { return (x + 255) & ~(size_t)255; }

// ---------------- edge bucketing (CSR keyed by r*N + dst) ----------------

__global__ void count_k(const int* __restrict__ ei, const int* __restrict__ et,
                        int* __restrict__ cnt) {
    int e = blockIdx.x * 256 + threadIdx.x;
    if (e < Ee) {
        int d = ei[Ee + e];
        int r = et[e];
        atomicAdd(&cnt[r * Nn + d], 1);
    }
}

__global__ __launch_bounds__(1024) void scan_k(const int* __restrict__ cnt,
                                               int* __restrict__ off,
                                               int* __restrict__ cursor,
                                               float* __restrict__ invc) {
    __shared__ int lds[1025];
    int t = threadIdx.x;
    const int chunk = (RN + 1023) / 1024;  // 391
    int base = t * chunk;
    int end = base + chunk; if (end > RN) end = RN;
    int s = 0;
    for (int i = base; i < end; ++i) s += cnt[i];
    lds[t] = s;
    __syncthreads();
    if (t == 0) {
        int run = 0;
        for (int i = 0; i < 1024; ++i) { int v = lds[i]; lds[i] = run; run += v; }
        lds[1024] = run;
    }
    __syncthreads();
    int run = lds[t];
    for (int i = base; i < end; ++i) {
        off[i] = run;
        cursor[i] = run;
        int c = cnt[i];
        invc[i] = 1.0f / (float)(c > 1 ? c : 1);
        run += c;
    }
    if (t == 0) off[RN] = lds[1024];
}

__global__ void scatter_k(const int* __restrict__ ei, const int* __restrict__ et,
                          int* __restrict__ cursor, int2* __restrict__ es) {
    int e = blockIdx.x * 256 + threadIdx.x;
    if (e < Ee) {
        int s = ei[e];
        int d = ei[Ee + e];
        int r = et[e];
        int p = atomicAdd(&cursor[r * Nn + d], 1);
        es[p] = make_int2(s, d);
    }
}

// ---------------- W_r = sum_b comp[r,b]*bases[b]; slot 8 = root ----------------

__global__ void makew_k(const float* __restrict__ bases, const float* __restrict__ comp,
                        const float* __restrict__ root, float* __restrict__ Wcat) {
    int idx = blockIdx.x * 256 + threadIdx.x;   // < L*9*16384
    int l = idx / (9 * 16384);
    int rem = idx % (9 * 16384);
    int s = rem >> 14;
    int io = rem & 16383;
    float v;
    if (s < 8) {
        v = 0.f;
#pragma unroll
        for (int b = 0; b < BB; ++b)
            v += comp[(l * RR + s) * BB + b] * bases[(l * BB + b) * 16384 + io];
    } else {
        v = root[l * 16384 + io];
    }
    Wcat[idx] = v;
}

// ---------------- lin1: relu(x @ W1 + b1) * temp0 -> hidden, cur ----------------

__global__ __launch_bounds__(256) void lin1_k(const float* __restrict__ x,
                                              const float* __restrict__ w1,
                                              const float* __restrict__ b1,
                                              const float* __restrict__ temp,
                                              float* __restrict__ hidden,
                                              float* __restrict__ cur) {
    __shared__ float Xt[32][130];   // transposed: Xt[k][row]
    __shared__ float Ws[32][128];
    int t = threadIdx.x;
    int v0 = blockIdx.x * 128;
    int ti = t >> 4, tj = t & 15;
    float acc[8][8];
#pragma unroll
    for (int i = 0; i < 8; ++i)
#pragma unroll
        for (int j = 0; j < 8; ++j) acc[i][j] = 0.f;

    for (int kc = 0; kc < INC; kc += 32) {
        __syncthreads();
        for (int idx = t; idx < 1024; idx += 256) {
            int row = idx >> 3, k4 = (idx & 7) << 2;
            float4 f = make_float4(0.f, 0.f, 0.f, 0.f);
            if (v0 + row < Nn) f = *(const float4*)(x + (size_t)(v0 + row) * INC + kc + k4);
            Xt[k4 + 0][row] = f.x; Xt[k4 + 1][row] = f.y;
            Xt[k4 + 2][row] = f.z; Xt[k4 + 3][row] = f.w;
        }
        for (int idx = t; idx < 1024; idx += 256) {
            int k = idx >> 5, c4 = (idx & 31) << 2;
            *(float4*)&Ws[k][c4] = *(const float4*)(w1 + (size_t)(kc + k) * HIDd + c4);
        }
        __syncthreads();
#pragma unroll 4
        for (int kk = 0; kk < 32; ++kk) {
            float a[8], b[8];
            *(float4*)&a[0] = *(const float4*)&Xt[kk][ti * 8];
            *(float4*)&a[4] = *(const float4*)&Xt[kk][ti * 8 + 4];
            *(float4*)&b[0] = *(const float4*)&Ws[kk][tj * 8];
            *(float4*)&b[4] = *(const float4*)&Ws[kk][tj * 8 + 4];
#pragma unroll
            for (int i = 0; i < 8; ++i)
#pragma unroll
                for (int j = 0; j < 8; ++j) acc[i][j] += a[i] * b[j];
        }
    }
    float t0 = temp[0];
    float bj[8];
#pragma unroll
    for (int j = 0; j < 8; ++j) bj[j] = b1[tj * 8 + j];
#pragma unroll
    for (int i = 0; i < 8; ++i) {
        int v = v0 + ti * 8 + i;
        if (v < Nn) {
            float vals[8];
#pragma unroll
            for (int j = 0; j < 8; ++j) {
                float val = acc[i][j] + bj[j];
                val = fmaxf(val, 0.f);
                vals[j] = t0 * val;
            }
            size_t base = (size_t)v * HIDd + tj * 8;
            *(float4*)(hidden + base)     = *(float4*)&vals[0];
            *(float4*)(hidden + base + 4) = *(float4*)&vals[4];
            *(float4*)(cur + base)        = *(float4*)&vals[0];
            *(float4*)(cur + base + 4)    = *(float4*)&vals[4];
        }
    }
}

// ---------------- fused RGCN layer: aggregate (LDS) + 9-chunk GEMM ----------------

__global__ __launch_bounds__(256) void layer_k(const float* __restrict__ cur,
                                               float* __restrict__ nxt,
                                               float* __restrict__ hidden,
                                               const float* __restrict__ Wl,
                                               const float* __restrict__ bias,
                                               const float* __restrict__ temp, int tidx,
                                               const int2* __restrict__ es,
                                               const int* __restrict__ off,
                                               const float* __restrict__ invc,
                                               int dorelu) {
    __shared__ float At[128][130];   // At[k][row] (transposed A tile)
    __shared__ float Bsm[128][128];
    int t = threadIdx.x;
    int v0 = blockIdx.x * 128;
    int nb = Nn - v0; if (nb > 128) nb = 128;
    int ti = t >> 4, tj = t & 15;
    float acc[8][8];
#pragma unroll
    for (int i = 0; i < 8; ++i)
#pragma unroll
        for (int j = 0; j < 8; ++j) acc[i][j] = 0.f;

    for (int s = 0; s < 9; ++s) {
        __syncthreads();   // previous GEMM done reading At/Bsm
        if (s < 8) {
            for (int idx = t; idx < 16384; idx += 256) At[idx >> 7][idx & 127] = 0.f;
        }
        // stage W slice for this chunk
        for (int idx = t; idx < 4096; idx += 256) {
            int k = idx >> 5, c4 = (idx & 31) << 2;
            *(float4*)&Bsm[k][c4] = *(const float4*)(Wl + (s << 14) + k * HIDd + c4);
        }
        __syncthreads();   // zeroing visible before atomics
        if (s < 8) {
            int b0 = s * Nn + v0;
            int eb = off[b0], ee = off[b0 + nb];
            int lane32 = t & 31;
            for (int i = eb + (t >> 5); i < ee; i += 8) {
                int2 e = es[i];
                float inv = invc[s * Nn + e.y];
                int row = e.y - v0;
                const float* sp = cur + (size_t)e.x * HIDd + lane32;
#pragma unroll
                for (int m = 0; m < 4; ++m) {
                    atomicAdd(&At[lane32 + m * 32][row], sp[m * 32] * inv);
                }
            }
        } else {
            // root chunk: At[k][row] = cur[v0+row][k]
            for (int idx = t; idx < 4096; idx += 256) {
                int row = idx >> 5, kl = idx & 31;
                bool ok = (v0 + row) < Nn;
                const float* sp = cur + (size_t)(v0 + row) * HIDd + kl;
#pragma unroll
                for (int m = 0; m < 4; ++m)
                    At[kl + m * 32][row] = ok ? sp[m * 32] : 0.f;
            }
        }
        __syncthreads();
#pragma unroll 2
        for (int k = 0; k < 128; ++k) {
            float a[8], b[8];
            *(float4*)&a[0] = *(const float4*)&At[k][ti * 8];
            *(float4*)&a[4] = *(const float4*)&At[k][ti * 8 + 4];
            *(float4*)&b[0] = *(const float4*)&Bsm[k][tj * 8];
            *(float4*)&b[4] = *(const float4*)&Bsm[k][tj * 8 + 4];
#pragma unroll
            for (int i = 0; i < 8; ++i)
#pragma unroll
                for (int j = 0; j < 8; ++j) acc[i][j] += a[i] * b[j];
        }
    }
    // epilogue: +bias, optional relu, write nxt, hidden += temp[tidx]*val
    float tl = temp[tidx];
    float bj[8];
#pragma unroll
    for (int j = 0; j < 8; ++j) bj[j] = bias[tj * 8 + j];
#pragma unroll
    for (int i = 0; i < 8; ++i) {
        int v = v0 + ti * 8 + i;
        if (v < Nn) {
            float vals[8];
#pragma unroll
            for (int j = 0; j < 8; ++j) {
                float val = acc[i][j] + bj[j];
                if (dorelu) val = fmaxf(val, 0.f);
                vals[j] = val;
            }
            size_t base = (size_t)v * HIDd + tj * 8;
            *(float4*)(nxt + base)     = *(float4*)&vals[0];
            *(float4*)(nxt + base + 4) = *(float4*)&vals[4];
            float4 h0 = *(float4*)(hidden + base);
            float4 h1 = *(float4*)(hidden + base + 4);
            h0.x += tl * vals[0]; h0.y += tl * vals[1];
            h0.z += tl * vals[2]; h0.w += tl * vals[3];
            h1.x += tl * vals[4]; h1.y += tl * vals[5];
            h1.z += tl * vals[6]; h1.w += tl * vals[7];
            *(float4*)(hidden + base)     = h0;
            *(float4*)(hidden + base + 4) = h1;
        }
    }
}

// ---------------- lin2: hidden @ W2 + b2 -> out [N,2] ----------------

__global__ __launch_bounds__(256) void lin2_k(const float* __restrict__ hidden,
                                              const float* __restrict__ w2,
                                              const float* __restrict__ b2,
                                              float* __restrict__ out) {
    __shared__ float ws[256];
    __shared__ float bs[2];
    int t = threadIdx.x;
    ws[t] = w2[t & 255];
    if (t < 2) bs[t] = b2[t];
    __syncthreads();
    int node = blockIdx.x * 64 + (t >> 2);
    int q = t & 3;
    float a0 = 0.f, a1 = 0.f;
    if (node < Nn) {
        const float* hp = hidden + (size_t)node * HIDd + q * 32;
#pragma unroll
        for (int kk = 0; kk < 32; kk += 4) {
            float4 h = *(const float4*)(hp + kk);
            int kb = (q * 32 + kk) * 2;
            a0 += h.x * ws[kb]     + h.y * ws[kb + 2] + h.z * ws[kb + 4] + h.w * ws[kb + 6];
            a1 += h.x * ws[kb + 1] + h.y * ws[kb + 3] + h.z * ws[kb + 5] + h.w * ws[kb + 7];
        }
    }
    a0 += __shfl_xor(a0, 1); a0 += __shfl_xor(a0, 2);
    a1 += __shfl_xor(a1, 1); a1 += __shfl_xor(a1, 2);
    if (node < Nn && q == 0) {
        out[node * 2 + 0] = a0 + bs[0];
        out[node * 2 + 1] = a1 + bs[1];
    }
}

// ---------------- host ----------------

extern "C" void kernel_launch(void* const* d_in, const int* in_sizes, int n_in,
                              void* d_out, int out_size, void* d_ws, size_t ws_size,
                              hipStream_t stream) {
    (void)in_sizes; (void)n_in; (void)out_size; (void)ws_size;
    const float* x        = (const float*)d_in[0];
    const int*   ei       = (const int*)d_in[1];
    const int*   et       = (const int*)d_in[2];
    const float* lin1_w   = (const float*)d_in[3];
    const float* lin1_b   = (const float*)d_in[4];
    const float* bases    = (const float*)d_in[5];
    const float* comp     = (const float*)d_in[6];
    const float* root     = (const float*)d_in[7];
    const float* bias_cv  = (const float*)d_in[8];
    const float* lin2_w   = (const float*)d_in[9];
    const float* lin2_b   = (const float*)d_in[10];
    const float* temp     = (const float*)d_in[11];
    float* out = (float*)d_out;

    char* w = (char*)d_ws;
    int*   off    = (int*)w;    w += align256((size_t)(RN + 1) * 4);
    int*   cnt    = (int*)w;    w += align256((size_t)RN * 4);
    int*   cursor = (int*)w;    w += align256((size_t)RN * 4);
    float* invc   = (float*)w;  w += align256((size_t)RN * 4);
    int2*  esort  = (int2*)w;   w += align256((size_t)Ee * 8);
    float* hidden = (float*)w;  w += align256((size_t)Nn * HIDd * 4);
    float* bufA   = (float*)w;  w += align256((size_t)Nn * HIDd * 4);
    float* bufB   = (float*)w;  w += align256((size_t)Nn * HIDd * 4);
    float* Wcat   = (float*)w;  w += align256((size_t)LL * 9 * HIDd * HIDd * 4);

    hipMemsetAsync(cnt, 0, (size_t)RN * 4, stream);
    count_k<<<(Ee + 255) / 256, 256, 0, stream>>>(ei, et, cnt);
    scan_k<<<1, 1024, 0, stream>>>(cnt, off, cursor, invc);
    scatter_k<<<(Ee + 255) / 256, 256, 0, stream>>>(ei, et, cursor, esort);
    makew_k<<<(LL * 9 * 16384) / 256, 256, 0, stream>>>(bases, comp, root, Wcat);
    lin1_k<<<(Nn + 127) / 128, 256, 0, stream>>>(x, lin1_w, lin1_b, temp, hidden, bufA);

    float* curp = bufA;
    float* nxtp = bufB;
    for (int l = 0; l < LL; ++l) {
        layer_k<<<(Nn + 127) / 128, 256, 0, stream>>>(
            curp, nxtp, hidden, Wcat + (size_t)l * 9 * 16384, bias_cv + l * HIDd,
            temp, l + 1, esort, off, invc, (l < LL - 1) ? 1 : 0);
        float* tmp = nxtp; nxtp = curp; curp = tmp;
    }
    lin2_k<<<(Nn + 63) / 64, 256, 0, stream>>>(hidden, lin2_w, lin2_b, out);
}

// Round 2
// 3242.632 us; speedup vs baseline: 1.3945x; 1.3945x over previous
//
#include <hip/hip_runtime.h>

#define Nn   50000
#define Ee   800000
#define INC  256
#define HIDd 128
#define RR   8
#define BB   4
#define LL   3
#define RN   (RR * Nn)   // 400000
#define NCH  391         // ceil(RN / 1024)

static inline size_t align256(size_t x) { return (x + 255) & ~(size_t)255; }

// ---------------- edge bucketing (CSR keyed by r*N + dst) ----------------

__global__ void count_k(const int* __restrict__ ei, const int* __restrict__ et,
                        int* __restrict__ cnt) {
    int e = blockIdx.x * 256 + threadIdx.x;
    if (e < Ee) {
        int d = ei[Ee + e];
        int r = et[e];
        atomicAdd(&cnt[r * Nn + d], 1);
    }
}

// 3-kernel parallel exclusive scan over cnt[RN] -> off/cursor, plus invc
__global__ __launch_bounds__(256) void chunksum_k(const int* __restrict__ cnt,
                                                  int* __restrict__ csum) {
    int c = blockIdx.x;
    int t = threadIdx.x;
    int idx4 = c * 256 + t;            // int4 index; RN/4 = 100000
    int s = 0;
    if (idx4 < RN / 4) {
        int4 v = ((const int4*)cnt)[idx4];
        s = v.x + v.y + v.z + v.w;
    }
#pragma unroll
    for (int o = 1; o < 64; o <<= 1) s += __shfl_xor(s, o);
    __shared__ int ws[4];
    if ((t & 63) == 0) ws[t >> 6] = s;
    __syncthreads();
    if (t == 0) csum[c] = ws[0] + ws[1] + ws[2] + ws[3];
}

__global__ __launch_bounds__(512) void chunkscan_k(const int* __restrict__ csum,
                                                   int* __restrict__ cbase,
                                                   int* __restrict__ off) {
    __shared__ int lds[NCH];
    int t = threadIdx.x;
    if (t < NCH) lds[t] = csum[t];
    __syncthreads();
    if (t == 0) {
        int run = 0;
        for (int i = 0; i < NCH; ++i) { int v = lds[i]; lds[i] = run; run += v; }
        off[RN] = run;   // == Ee
    }
    __syncthreads();
    if (t < NCH) cbase[t] = lds[t];
}

__global__ __launch_bounds__(256) void writeoff_k(const int* __restrict__ cnt,
                                                  const int* __restrict__ cbase,
                                                  int* __restrict__ off,
                                                  int* __restrict__ cursor,
                                                  float* __restrict__ invc) {
    int c = blockIdx.x;
    int t = threadIdx.x;
    int idx4 = c * 256 + t;
    bool ok = idx4 < RN / 4;
    int4 v = make_int4(0, 0, 0, 0);
    if (ok) v = ((const int4*)cnt)[idx4];
    int s = v.x + v.y + v.z + v.w;
    int lane = t & 63;
    int incl = s;
#pragma unroll
    for (int o = 1; o < 64; o <<= 1) {
        int u = __shfl_up(incl, o);
        if (lane >= o) incl += u;
    }
    __shared__ int wsum[4];
    if (lane == 63) wsum[t >> 6] = incl;
    __syncthreads();
    int w = t >> 6;
    int wpre = 0;
    if (w > 0) wpre += wsum[0];
    if (w > 1) wpre += wsum[1];
    if (w > 2) wpre += wsum[2];
    int excl = cbase[c] + wpre + incl - s;
    if (ok) {
        int o0 = excl;
        int o1 = o0 + v.x;
        int o2 = o1 + v.y;
        int o3 = o2 + v.z;
        int4 ov = make_int4(o0, o1, o2, o3);
        ((int4*)off)[idx4] = ov;
        ((int4*)cursor)[idx4] = ov;
        float4 iv;
        iv.x = 1.0f / (float)(v.x > 1 ? v.x : 1);
        iv.y = 1.0f / (float)(v.y > 1 ? v.y : 1);
        iv.z = 1.0f / (float)(v.z > 1 ? v.z : 1);
        iv.w = 1.0f / (float)(v.w > 1 ? v.w : 1);
        ((float4*)invc)[idx4] = iv;
    }
}

__global__ void scatter_k(const int* __restrict__ ei, const int* __restrict__ et,
                          int* __restrict__ cursor, int2* __restrict__ es) {
    int e = blockIdx.x * 256 + threadIdx.x;
    if (e < Ee) {
        int s = ei[e];
        int d = ei[Ee + e];
        int r = et[e];
        int p = atomicAdd(&cursor[r * Nn + d], 1);
        es[p] = make_int2(s, d);
    }
}

// ---------------- W_r = sum_b comp[r,b]*bases[b]; slot 8 = root ----------------

__global__ void makew_k(const float* __restrict__ bases, const float* __restrict__ comp,
                        const float* __restrict__ root, float* __restrict__ Wcat) {
    int idx = blockIdx.x * 256 + threadIdx.x;   // < L*9*16384
    int l = idx / (9 * 16384);
    int rem = idx % (9 * 16384);
    int s = rem >> 14;
    int io = rem & 16383;
    float v;
    if (s < 8) {
        v = 0.f;
#pragma unroll
        for (int b = 0; b < BB; ++b)
            v += comp[(l * RR + s) * BB + b] * bases[(l * BB + b) * 16384 + io];
    } else {
        v = root[l * 16384 + io];
    }
    Wcat[idx] = v;
}

// ---------------- lin1: relu(x @ W1 + b1) * temp0 -> hidden, cur ----------------

__global__ __launch_bounds__(256) void lin1_k(const float* __restrict__ x,
                                              const float* __restrict__ w1,
                                              const float* __restrict__ b1,
                                              const float* __restrict__ temp,
                                              float* __restrict__ hidden,
                                              float* __restrict__ cur) {
    __shared__ float Xt[32][130];   // transposed: Xt[k][row]
    __shared__ float Ws[32][128];
    int t = threadIdx.x;
    int v0 = blockIdx.x * 128;
    int ti = t >> 4, tj = t & 15;
    float acc[8][8];
#pragma unroll
    for (int i = 0; i < 8; ++i)
#pragma unroll
        for (int j = 0; j < 8; ++j) acc[i][j] = 0.f;

    for (int kc = 0; kc < INC; kc += 32) {
        __syncthreads();
        for (int idx = t; idx < 1024; idx += 256) {
            int row = idx >> 3, k4 = (idx & 7) << 2;
            float4 f = make_float4(0.f, 0.f, 0.f, 0.f);
            if (v0 + row < Nn) f = *(const float4*)(x + (size_t)(v0 + row) * INC + kc + k4);
            Xt[k4 + 0][row] = f.x; Xt[k4 + 1][row] = f.y;
            Xt[k4 + 2][row] = f.z; Xt[k4 + 3][row] = f.w;
        }
        for (int idx = t; idx < 1024; idx += 256) {
            int k = idx >> 5, c4 = (idx & 31) << 2;
            *(float4*)&Ws[k][c4] = *(const float4*)(w1 + (size_t)(kc + k) * HIDd + c4);
        }
        __syncthreads();
#pragma unroll 4
        for (int kk = 0; kk < 32; ++kk) {
            float a[8], b[8];
            *(float4*)&a[0] = *(const float4*)&Xt[kk][ti * 8];
            *(float4*)&a[4] = *(const float4*)&Xt[kk][ti * 8 + 4];
            *(float4*)&b[0] = *(const float4*)&Ws[kk][tj * 8];
            *(float4*)&b[4] = *(const float4*)&Ws[kk][tj * 8 + 4];
#pragma unroll
            for (int i = 0; i < 8; ++i)
#pragma unroll
                for (int j = 0; j < 8; ++j) acc[i][j] += a[i] * b[j];
        }
    }
    float t0 = temp[0];
    float bj[8];
#pragma unroll
    for (int j = 0; j < 8; ++j) bj[j] = b1[tj * 8 + j];
#pragma unroll
    for (int i = 0; i < 8; ++i) {
        int v = v0 + ti * 8 + i;
        if (v < Nn) {
            float vals[8];
#pragma unroll
            for (int j = 0; j < 8; ++j) {
                float val = acc[i][j] + bj[j];
                val = fmaxf(val, 0.f);
                vals[j] = t0 * val;
            }
            size_t base = (size_t)v * HIDd + tj * 8;
            *(float4*)(hidden + base)     = *(float4*)&vals[0];
            *(float4*)(hidden + base + 4) = *(float4*)&vals[4];
            *(float4*)(cur + base)        = *(float4*)&vals[0];
            *(float4*)(cur + base + 4)    = *(float4*)&vals[4];
        }
    }
}

// ---------------- fused RGCN layer: aggregate (LDS) + 9-chunk GEMM ----------------

__global__ __launch_bounds__(256) void layer_k(const float* __restrict__ cur,
                                               float* __restrict__ nxt,
                                               float* __restrict__ hidden,
                                               const float* __restrict__ Wl,
                                               const float* __restrict__ bias,
                                               const float* __restrict__ temp, int tidx,
                                               const int2* __restrict__ es,
                                               const int* __restrict__ off,
                                               const float* __restrict__ invc,
                                               int dorelu) {
    __shared__ float At[128][130];   // At[k][row] (transposed A tile)
    __shared__ float Bsm[128][128];
    int t = threadIdx.x;
    int v0 = blockIdx.x * 128;
    int nb = Nn - v0; if (nb > 128) nb = 128;
    int ti = t >> 4, tj = t & 15;
    float acc[8][8];
#pragma unroll
    for (int i = 0; i < 8; ++i)
#pragma unroll
        for (int j = 0; j < 8; ++j) acc[i][j] = 0.f;

    for (int s = 0; s < 9; ++s) {
        __syncthreads();   // previous GEMM done reading At/Bsm
        if (s < 8) {
            for (int idx = t; idx < 16384; idx += 256) At[idx >> 7][idx & 127] = 0.f;
        }
        // stage W slice for this chunk
        for (int idx = t; idx < 4096; idx += 256) {
            int k = idx >> 5, c4 = (idx & 31) << 2;
            *(float4*)&Bsm[k][c4] = *(const float4*)(Wl + (s << 14) + k * HIDd + c4);
        }
        __syncthreads();   // zeroing visible before atomics
        if (s < 8) {
            int b0 = s * Nn + v0;
            int eb = off[b0], ee = off[b0 + nb];
            int lane32 = t & 31;
            for (int i = eb + (t >> 5); i < ee; i += 8) {
                int2 e = es[i];
                float inv = invc[s * Nn + e.y];
                int row = e.y - v0;
                const float* sp = cur + (size_t)e.x * HIDd + lane32;
#pragma unroll
                for (int m = 0; m < 4; ++m) {
                    atomicAdd(&At[lane32 + m * 32][row], sp[m * 32] * inv);
                }
            }
        } else {
            // root chunk: At[k][row] = cur[v0+row][k]
            for (int idx = t; idx < 4096; idx += 256) {
                int row = idx >> 5, kl = idx & 31;
                bool ok = (v0 + row) < Nn;
                const float* sp = cur + (size_t)(v0 + row) * HIDd + kl;
#pragma unroll
                for (int m = 0; m < 4; ++m)
                    At[kl + m * 32][row] = ok ? sp[m * 32] : 0.f;
            }
        }
        __syncthreads();
#pragma unroll 2
        for (int k = 0; k < 128; ++k) {
            float a[8], b[8];
            *(float4*)&a[0] = *(const float4*)&At[k][ti * 8];
            *(float4*)&a[4] = *(const float4*)&At[k][ti * 8 + 4];
            *(float4*)&b[0] = *(const float4*)&Bsm[k][tj * 8];
            *(float4*)&b[4] = *(const float4*)&Bsm[k][tj * 8 + 4];
#pragma unroll
            for (int i = 0; i < 8; ++i)
#pragma unroll
                for (int j = 0; j < 8; ++j) acc[i][j] += a[i] * b[j];
        }
    }
    // epilogue: +bias, optional relu, write nxt, hidden += temp[tidx]*val
    float tl = temp[tidx];
    float bj[8];
#pragma unroll
    for (int j = 0; j < 8; ++j) bj[j] = bias[tj * 8 + j];
#pragma unroll
    for (int i = 0; i < 8; ++i) {
        int v = v0 + ti * 8 + i;
        if (v < Nn) {
            float vals[8];
#pragma unroll
            for (int j = 0; j < 8; ++j) {
                float val = acc[i][j] + bj[j];
                if (dorelu) val = fmaxf(val, 0.f);
                vals[j] = val;
            }
            size_t base = (size_t)v * HIDd + tj * 8;
            *(float4*)(nxt + base)     = *(float4*)&vals[0];
            *(float4*)(nxt + base + 4) = *(float4*)&vals[4];
            float4 h0 = *(float4*)(hidden + base);
            float4 h1 = *(float4*)(hidden + base + 4);
            h0.x += tl * vals[0]; h0.y += tl * vals[1];
            h0.z += tl * vals[2]; h0.w += tl * vals[3];
            h1.x += tl * vals[4]; h1.y += tl * vals[5];
            h1.z += tl * vals[6]; h1.w += tl * vals[7];
            *(float4*)(hidden + base)     = h0;
            *(float4*)(hidden + base + 4) = h1;
        }
    }
}

// ---------------- lin2: hidden @ W2 + b2 -> out [N,2] ----------------

__global__ __launch_bounds__(256) void lin2_k(const float* __restrict__ hidden,
                                              const float* __restrict__ w2,
                                              const float* __restrict__ b2,
                                              float* __restrict__ out) {
    __shared__ float ws[256];
    __shared__ float bs[2];
    int t = threadIdx.x;
    ws[t] = w2[t & 255];
    if (t < 2) bs[t] = b2[t];
    __syncthreads();
    int node = blockIdx.x * 64 + (t >> 2);
    int q = t & 3;
    float a0 = 0.f, a1 = 0.f;
    if (node < Nn) {
        const float* hp = hidden + (size_t)node * HIDd + q * 32;
#pragma unroll
        for (int kk = 0; kk < 32; kk += 4) {
            float4 h = *(const float4*)(hp + kk);
            int kb = (q * 32 + kk) * 2;
            a0 += h.x * ws[kb]     + h.y * ws[kb + 2] + h.z * ws[kb + 4] + h.w * ws[kb + 6];
            a1 += h.x * ws[kb + 1] + h.y * ws[kb + 3] + h.z * ws[kb + 5] + h.w * ws[kb + 7];
        }
    }
    a0 += __shfl_xor(a0, 1); a0 += __shfl_xor(a0, 2);
    a1 += __shfl_xor(a1, 1); a1 += __shfl_xor(a1, 2);
    if (node < Nn && q == 0) {
        out[node * 2 + 0] = a0 + bs[0];
        out[node * 2 + 1] = a1 + bs[1];
    }
}

// ---------------- host ----------------

extern "C" void kernel_launch(void* const* d_in, const int* in_sizes, int n_in,
                              void* d_out, int out_size, void* d_ws, size_t ws_size,
                              hipStream_t stream) {
    (void)in_sizes; (void)n_in; (void)out_size; (void)ws_size;
    const float* x        = (const float*)d_in[0];
    const int*   ei       = (const int*)d_in[1];
    const int*   et       = (const int*)d_in[2];
    const float* lin1_w   = (const float*)d_in[3];
    const float* lin1_b   = (const float*)d_in[4];
    const float* bases    = (const float*)d_in[5];
    const float* comp     = (const float*)d_in[6];
    const float* root     = (const float*)d_in[7];
    const float* bias_cv  = (const float*)d_in[8];
    const float* lin2_w   = (const float*)d_in[9];
    const float* lin2_b   = (const float*)d_in[10];
    const float* temp     = (const float*)d_in[11];
    float* out = (float*)d_out;

    char* w = (char*)d_ws;
    int*   off    = (int*)w;    w += align256((size_t)(RN + 1) * 4);
    int*   cnt    = (int*)w;    w += align256((size_t)RN * 4);
    int*   cursor = (int*)w;    w += align256((size_t)RN * 4);
    float* invc   = (float*)w;  w += align256((size_t)RN * 4);
    int*   csum   = (int*)w;    w += align256((size_t)NCH * 4);
    int*   cbase  = (int*)w;    w += align256((size_t)NCH * 4);
    int2*  esort  = (int2*)w;   w += align256((size_t)Ee * 8);
    float* hidden = (float*)w;  w += align256((size_t)Nn * HIDd * 4);
    float* bufA   = (float*)w;  w += align256((size_t)Nn * HIDd * 4);
    float* bufB   = (float*)w;  w += align256((size_t)Nn * HIDd * 4);
    float* Wcat   = (float*)w;  w += align256((size_t)LL * 9 * HIDd * HIDd * 4);

    hipMemsetAsync(cnt, 0, (size_t)RN * 4, stream);
    count_k<<<(Ee + 255) / 256, 256, 0, stream>>>(ei, et, cnt);
    chunksum_k<<<NCH, 256, 0, stream>>>(cnt, csum);
    chunkscan_k<<<1, 512, 0, stream>>>(csum, cbase, off);
    writeoff_k<<<NCH, 256, 0, stream>>>(cnt, cbase, off, cursor, invc);
    scatter_k<<<(Ee + 255) / 256, 256, 0, stream>>>(ei, et, cursor, esort);
    makew_k<<<(LL * 9 * 16384) / 256, 256, 0, stream>>>(bases, comp, root, Wcat);
    lin1_k<<<(Nn + 127) / 128, 256, 0, stream>>>(x, lin1_w, lin1_b, temp, hidden, bufA);

    float* curp = bufA;
    float* nxtp = bufB;
    for (int l = 0; l < LL; ++l) {
        layer_k<<<(Nn + 127) / 128, 256, 0, stream>>>(
            curp, nxtp, hidden, Wcat + (size_t)l * 9 * 16384, bias_cv + l * HIDd,
            temp, l + 1, esort, off, invc, (l < LL - 1) ? 1 : 0);
        float* tmp = nxtp; nxtp = curp; curp = tmp;
    }
    lin2_k<<<(Nn + 63) / 64, 256, 0, stream>>>(hidden, lin2_w, lin2_b, out);
}

// Round 6
// 646.040 us; speedup vs baseline: 6.9992x; 5.0192x over previous
//
#include <hip/hip_runtime.h>

#define Nn   50000
#define Ee   800000
#define INC  256
#define HIDd 128
#define RR   8
#define BB   4
#define LL   3
#define RN   (RR * Nn)   // 400000
#define NCH  391         // ceil(RN / 1024)

typedef _Float16 f16;
typedef _Float16 f16x2 __attribute__((ext_vector_type(2)));
typedef _Float16 f16x8 __attribute__((ext_vector_type(8)));
typedef float    f32x4 __attribute__((ext_vector_type(4)));

static inline size_t align256(size_t x) { return (x + 255) & ~(size_t)255; }

// ---------------- edge bucketing (CSR keyed by r*N + dst) ----------------

__global__ void count_k(const int* __restrict__ ei, const int* __restrict__ et,
                        int* __restrict__ cnt) {
    int e = blockIdx.x * 256 + threadIdx.x;
    if (e < Ee) {
        int d = ei[Ee + e];
        int r = et[e];
        atomicAdd(&cnt[r * Nn + d], 1);
    }
}

__global__ __launch_bounds__(256) void chunksum_k(const int* __restrict__ cnt,
                                                  int* __restrict__ csum) {
    int c = blockIdx.x;
    int t = threadIdx.x;
    int idx4 = c * 256 + t;            // int4 index; RN/4 = 100000
    int s = 0;
    if (idx4 < RN / 4) {
        int4 v = ((const int4*)cnt)[idx4];
        s = v.x + v.y + v.z + v.w;
    }
#pragma unroll
    for (int o = 1; o < 64; o <<= 1) s += __shfl_xor(s, o);
    __shared__ int ws[4];
    if ((t & 63) == 0) ws[t >> 6] = s;
    __syncthreads();
    if (t == 0) csum[c] = ws[0] + ws[1] + ws[2] + ws[3];
}

__global__ __launch_bounds__(512) void chunkscan_k(const int* __restrict__ csum,
                                                   int* __restrict__ cbase,
                                                   int* __restrict__ off) {
    __shared__ int lds[NCH];
    int t = threadIdx.x;
    if (t < NCH) lds[t] = csum[t];
    __syncthreads();
    if (t == 0) {
        int run = 0;
        for (int i = 0; i < NCH; ++i) { int v = lds[i]; lds[i] = run; run += v; }
        off[RN] = run;   // == Ee
    }
    __syncthreads();
    if (t < NCH) cbase[t] = lds[t];
}

__global__ __launch_bounds__(256) void writeoff_k(const int* __restrict__ cnt,
                                                  const int* __restrict__ cbase,
                                                  int* __restrict__ off,
                                                  int* __restrict__ cursor,
                                                  float* __restrict__ invc) {
    int c = blockIdx.x;
    int t = threadIdx.x;
    int idx4 = c * 256 + t;
    bool ok = idx4 < RN / 4;
    int4 v = make_int4(0, 0, 0, 0);
    if (ok) v = ((const int4*)cnt)[idx4];
    int s = v.x + v.y + v.z + v.w;
    int lane = t & 63;
    int incl = s;
#pragma unroll
    for (int o = 1; o < 64; o <<= 1) {
        int u = __shfl_up(incl, o);
        if (lane >= o) incl += u;
    }
    __shared__ int wsum[4];
    if (lane == 63) wsum[t >> 6] = incl;
    __syncthreads();
    int w = t >> 6;
    int wpre = 0;
    if (w > 0) wpre += wsum[0];
    if (w > 1) wpre += wsum[1];
    if (w > 2) wpre += wsum[2];
    int excl = cbase[c] + wpre + incl - s;
    if (ok) {
        int o0 = excl;
        int o1 = o0 + v.x;
        int o2 = o1 + v.y;
        int o3 = o2 + v.z;
        int4 ov = make_int4(o0, o1, o2, o3);
        ((int4*)off)[idx4] = ov;
        ((int4*)cursor)[idx4] = ov;
        float4 iv;
        iv.x = 1.0f / (float)(v.x > 1 ? v.x : 1);
        iv.y = 1.0f / (float)(v.y > 1 ? v.y : 1);
        iv.z = 1.0f / (float)(v.z > 1 ? v.z : 1);
        iv.w = 1.0f / (float)(v.w > 1 ? v.w : 1);
        ((float4*)invc)[idx4] = iv;
    }
}

__global__ void scatter_k(const int* __restrict__ ei, const int* __restrict__ et,
                          int* __restrict__ cursor, int* __restrict__ es) {
    int e = blockIdx.x * 256 + threadIdx.x;
    if (e < Ee) {
        int s = ei[e];
        int d = ei[Ee + e];
        int r = et[e];
        int p = atomicAdd(&cursor[r * Nn + d], 1);
        es[p] = s;
    }
}

// ------- W^T (fp16): chunk 0 = root^T, chunks 1..4 = bases[b]^T, per layer -------

__global__ void makewT_k(const float* __restrict__ bases, const float* __restrict__ root,
                         f16* __restrict__ WT) {
    int idx = blockIdx.x * 256 + threadIdx.x;   // < L*5*16384
    int l = idx / (5 * 16384);
    int rem = idx % (5 * 16384);
    int c = rem >> 14;
    int n = (rem >> 7) & 127;
    int k = rem & 127;
    float v = (c == 0) ? root[l * 16384 + k * 128 + n]
                       : bases[((l * BB + (c - 1)) << 14) + k * 128 + n];
    WT[idx] = (f16)v;
}

// ---------------- lin1: relu(x @ W1 + b1) * temp0 -> hidden(f32), curh(f16) ----------------

__global__ __launch_bounds__(256) void lin1_k(const float* __restrict__ x,
                                              const float* __restrict__ w1,
                                              const float* __restrict__ b1,
                                              const float* __restrict__ temp,
                                              float* __restrict__ hidden,
                                              f16* __restrict__ curh) {
    __shared__ float Xt[32][130];
    __shared__ float Ws[32][128];
    int t = threadIdx.x;
    int v0 = blockIdx.x * 128;
    int ti = t >> 4, tj = t & 15;
    float acc[8][8];
#pragma unroll
    for (int i = 0; i < 8; ++i)
#pragma unroll
        for (int j = 0; j < 8; ++j) acc[i][j] = 0.f;

    for (int kc = 0; kc < INC; kc += 32) {
        __syncthreads();
        for (int idx = t; idx < 1024; idx += 256) {
            int row = idx >> 3, k4 = (idx & 7) << 2;
            float4 f = make_float4(0.f, 0.f, 0.f, 0.f);
            if (v0 + row < Nn) f = *(const float4*)(x + (size_t)(v0 + row) * INC + kc + k4);
            Xt[k4 + 0][row] = f.x; Xt[k4 + 1][row] = f.y;
            Xt[k4 + 2][row] = f.z; Xt[k4 + 3][row] = f.w;
        }
        for (int idx = t; idx < 1024; idx += 256) {
            int k = idx >> 5, c4 = (idx & 31) << 2;
            *(float4*)&Ws[k][c4] = *(const float4*)(w1 + (size_t)(kc + k) * HIDd + c4);
        }
        __syncthreads();
#pragma unroll 4
        for (int kk = 0; kk < 32; ++kk) {
            float a[8], b[8];
            *(float4*)&a[0] = *(const float4*)&Xt[kk][ti * 8];
            *(float4*)&a[4] = *(const float4*)&Xt[kk][ti * 8 + 4];
            *(float4*)&b[0] = *(const float4*)&Ws[kk][tj * 8];
            *(float4*)&b[4] = *(const float4*)&Ws[kk][tj * 8 + 4];
#pragma unroll
            for (int i = 0; i < 8; ++i)
#pragma unroll
                for (int j = 0; j < 8; ++j) acc[i][j] += a[i] * b[j];
        }
    }
    float t0 = temp[0];
    float bj[8];
#pragma unroll
    for (int j = 0; j < 8; ++j) bj[j] = b1[tj * 8 + j];
#pragma unroll
    for (int i = 0; i < 8; ++i) {
        int v = v0 + ti * 8 + i;
        if (v < Nn) {
            float vals[8];
            f16x8 hv;
#pragma unroll
            for (int j = 0; j < 8; ++j) {
                float val = acc[i][j] + bj[j];
                val = fmaxf(val, 0.f);
                vals[j] = t0 * val;
                hv[j] = (f16)vals[j];
            }
            size_t base = (size_t)v * HIDd + tj * 8;
            *(float4*)(hidden + base)     = *(float4*)&vals[0];
            *(float4*)(hidden + base + 4) = *(float4*)&vals[4];
            *(f16x8*)(curh + base) = hv;
        }
    }
}

// ------- aggregation: wave per dst node, register accumulation, basis trick -------
// aggh[d][b][k] (f16), b=0..3: Sum_r comp[r,b] * mean_r(curh[src])

__global__ __launch_bounds__(256) void agg_k(const f16* __restrict__ curh,
                                             const int* __restrict__ es,
                                             const int* __restrict__ off,
                                             const float* __restrict__ invc,
                                             const float* __restrict__ comp_l,
                                             f16* __restrict__ aggh) {
    int t = threadIdx.x;
    int d = blockIdx.x * 4 + (t >> 6);
    int lane = t & 63;
    float2 acc[4];
#pragma unroll
    for (int b = 0; b < 4; ++b) { acc[b].x = 0.f; acc[b].y = 0.f; }

    int e0[8], e1[8];
    float iv[8];
#pragma unroll
    for (int r = 0; r < 8; ++r) {
        int base = r * Nn + d;
        e0[r] = off[base];
        e1[r] = off[base + 1];
        iv[r] = invc[base];
    }
#pragma unroll
    for (int r = 0; r < 8; ++r) {
        float rx = 0.f, ry = 0.f;
        for (int e = e0[r]; e < e1[r]; ++e) {
            int s = es[e];
            f16x2 v = *(const f16x2*)(curh + (size_t)s * HIDd + lane * 2);
            rx += (float)v[0];
            ry += (float)v[1];
        }
#pragma unroll
        for (int b = 0; b < 4; ++b) {
            float cb = comp_l[r * 4 + b] * iv[r];
            acc[b].x += cb * rx;
            acc[b].y += cb * ry;
        }
    }
    f16* op = aggh + (size_t)d * 512 + lane * 2;
#pragma unroll
    for (int b = 0; b < 4; ++b) {
        f16x2 o;
        o[0] = (f16)acc[b].x;
        o[1] = (f16)acc[b].y;
        *(f16x2*)(op + b * HIDd) = o;
    }
}

// ------- dense fp16 MFMA GEMM: C[128 tile] = [curh | agg0..3] @ WT^T, K=640 -------

__global__ __launch_bounds__(256, 2) void gemm_k(const f16* __restrict__ curh,
                                                 const f16* __restrict__ aggh,
                                                 const f16* __restrict__ WTl,
                                                 const float* __restrict__ bias,
                                                 const float* __restrict__ temp, int tidx,
                                                 f16* __restrict__ curh_next,
                                                 float* __restrict__ hidden,
                                                 int dorelu) {
    __shared__ f16 Ah[128 * 136];
    __shared__ f16 Bh[128 * 136];
    int t = threadIdx.x;
    int v0 = blockIdx.x * 128;
    int w = t >> 6, lane = t & 63;
    int wr = w >> 1, wc = w & 1;
    int l15 = lane & 15, l4 = lane >> 4;
    int srow = t >> 1, sseg = t & 1;    // staging: row, 64-half segment

    f32x4 acc[4][4] = {};

    for (int c = 0; c < 5; ++c) {
        __syncthreads();
        // stage A (128 rows x 128 halves)
        {
            f16* dst = Ah + srow * 136 + sseg * 64;
            if (v0 + srow < Nn) {
                const f16* src = (c == 0)
                    ? curh + (size_t)(v0 + srow) * HIDd + sseg * 64
                    : aggh + (size_t)(v0 + srow) * 512 + (c - 1) * HIDd + sseg * 64;
#pragma unroll
                for (int j = 0; j < 8; ++j)
                    *(f16x8*)(dst + j * 8) = *(const f16x8*)(src + j * 8);
            } else {
                f16x8 z = {};
#pragma unroll
                for (int j = 0; j < 8; ++j)
                    *(f16x8*)(dst + j * 8) = z;
            }
        }
        // stage B^T (128 n-rows x 128 k)
        {
            const f16* src = WTl + (c << 14) + srow * HIDd + sseg * 64;
            f16* dst = Bh + srow * 136 + sseg * 64;
#pragma unroll
            for (int j = 0; j < 8; ++j)
                *(f16x8*)(dst + j * 8) = *(const f16x8*)(src + j * 8);
        }
        __syncthreads();
#pragma unroll
        for (int ks = 0; ks < 4; ++ks) {
            f16x8 af[4], bf[4];
#pragma unroll
            for (int mf = 0; mf < 4; ++mf)
                af[mf] = *(const f16x8*)(Ah + (wr * 64 + mf * 16 + l15) * 136 + ks * 32 + l4 * 8);
#pragma unroll
            for (int nf = 0; nf < 4; ++nf)
                bf[nf] = *(const f16x8*)(Bh + (wc * 64 + nf * 16 + l15) * 136 + ks * 32 + l4 * 8);
#pragma unroll
            for (int mf = 0; mf < 4; ++mf)
#pragma unroll
                for (int nf = 0; nf < 4; ++nf)
                    acc[mf][nf] = __builtin_amdgcn_mfma_f32_16x16x32_f16(af[mf], bf[nf], acc[mf][nf], 0, 0, 0);
        }
    }

    // epilogue: bias, relu, f16 into Ah (reuse), then coalesced writes
    __syncthreads();
    float tl = temp[tidx];
    float bs[4];
#pragma unroll
    for (int nf = 0; nf < 4; ++nf) bs[nf] = bias[wc * 64 + nf * 16 + l15];
#pragma unroll
    for (int mf = 0; mf < 4; ++mf)
#pragma unroll
        for (int nf = 0; nf < 4; ++nf)
#pragma unroll
            for (int j = 0; j < 4; ++j) {
                float val = acc[mf][nf][j] + bs[nf];
                if (dorelu) val = fmaxf(val, 0.f);
                Ah[(wr * 64 + mf * 16 + l4 * 4 + j) * 136 + wc * 64 + nf * 16 + l15] = (f16)val;
            }
    __syncthreads();
    if (v0 + srow < Nn) {
        size_t gb = (size_t)(v0 + srow) * HIDd + sseg * 64;
        const f16* cr = Ah + srow * 136 + sseg * 64;
#pragma unroll
        for (int j = 0; j < 8; ++j)
            *(f16x8*)(curh_next + gb + j * 8) = *(const f16x8*)(cr + j * 8);
        float* hp = hidden + gb;
#pragma unroll
        for (int j = 0; j < 16; ++j) {
            float4 h = *(float4*)(hp + j * 4);
            h.x += tl * (float)cr[j * 4 + 0];
            h.y += tl * (float)cr[j * 4 + 1];
            h.z += tl * (float)cr[j * 4 + 2];
            h.w += tl * (float)cr[j * 4 + 3];
            *(float4*)(hp + j * 4) = h;
        }
    }
}

// ---------------- lin2: hidden @ W2 + b2 -> out [N,2] ----------------

__global__ __launch_bounds__(256) void lin2_k(const float* __restrict__ hidden,
                                              const float* __restrict__ w2,
                                              const float* __restrict__ b2,
                                              float* __restrict__ out) {
    __shared__ float ws[256];
    __shared__ float bs[2];
    int t = threadIdx.x;
    ws[t] = w2[t & 255];
    if (t < 2) bs[t] = b2[t];
    __syncthreads();
    int node = blockIdx.x * 64 + (t >> 2);
    int q = t & 3;
    float a0 = 0.f, a1 = 0.f;
    if (node < Nn) {
        const float* hp = hidden + (size_t)node * HIDd + q * 32;
#pragma unroll
        for (int kk = 0; kk < 32; kk += 4) {
            float4 h = *(const float4*)(hp + kk);
            int kb = (q * 32 + kk) * 2;
            a0 += h.x * ws[kb]     + h.y * ws[kb + 2] + h.z * ws[kb + 4] + h.w * ws[kb + 6];
            a1 += h.x * ws[kb + 1] + h.y * ws[kb + 3] + h.z * ws[kb + 5] + h.w * ws[kb + 7];
        }
    }
    a0 += __shfl_xor(a0, 1); a0 += __shfl_xor(a0, 2);
    a1 += __shfl_xor(a1, 1); a1 += __shfl_xor(a1, 2);
    if (node < Nn && q == 0) {
        out[node * 2 + 0] = a0 + bs[0];
        out[node * 2 + 1] = a1 + bs[1];
    }
}

// ---------------- host ----------------

extern "C" void kernel_launch(void* const* d_in, const int* in_sizes, int n_in,
                              void* d_out, int out_size, void* d_ws, size_t ws_size,
                              hipStream_t stream) {
    (void)in_sizes; (void)n_in; (void)out_size; (void)ws_size;
    const float* x        = (const float*)d_in[0];
    const int*   ei       = (const int*)d_in[1];
    const int*   et       = (const int*)d_in[2];
    const float* lin1_w   = (const float*)d_in[3];
    const float* lin1_b   = (const float*)d_in[4];
    const float* bases    = (const float*)d_in[5];
    const float* comp     = (const float*)d_in[6];
    const float* root     = (const float*)d_in[7];
    const float* bias_cv  = (const float*)d_in[8];
    const float* lin2_w   = (const float*)d_in[9];
    const float* lin2_b   = (const float*)d_in[10];
    const float* temp     = (const float*)d_in[11];
    float* out = (float*)d_out;

    char* w = (char*)d_ws;
    int*   off    = (int*)w;    w += align256((size_t)(RN + 1) * 4);
    int*   cnt    = (int*)w;    w += align256((size_t)RN * 4);
    int*   cursor = (int*)w;    w += align256((size_t)RN * 4);
    float* invc   = (float*)w;  w += align256((size_t)RN * 4);
    int*   csum   = (int*)w;    w += align256((size_t)NCH * 4);
    int*   cbase  = (int*)w;    w += align256((size_t)NCH * 4);
    int*   es     = (int*)w;    w += align256((size_t)Ee * 4);
    f16*   WT     = (f16*)w;    w += align256((size_t)LL * 5 * HIDd * HIDd * 2);
    float* hidden = (float*)w;  w += align256((size_t)Nn * HIDd * 4);
    f16*   curhA  = (f16*)w;    w += align256((size_t)Nn * HIDd * 2);
    f16*   curhB  = (f16*)w;    w += align256((size_t)Nn * HIDd * 2);
    f16*   aggh   = (f16*)w;    w += align256((size_t)Nn * 4 * HIDd * 2);

    hipMemsetAsync(cnt, 0, (size_t)RN * 4, stream);
    count_k<<<(Ee + 255) / 256, 256, 0, stream>>>(ei, et, cnt);
    chunksum_k<<<NCH, 256, 0, stream>>>(cnt, csum);
    chunkscan_k<<<1, 512, 0, stream>>>(csum, cbase, off);
    writeoff_k<<<NCH, 256, 0, stream>>>(cnt, cbase, off, cursor, invc);
    scatter_k<<<(Ee + 255) / 256, 256, 0, stream>>>(ei, et, cursor, es);
    makewT_k<<<(LL * 5 * 16384) / 256, 256, 0, stream>>>(bases, root, WT);
    lin1_k<<<(Nn + 127) / 128, 256, 0, stream>>>(x, lin1_w, lin1_b, temp, hidden, curhA);

    f16* curp = curhA;
    f16* nxtp = curhB;
    for (int l = 0; l < LL; ++l) {
        agg_k<<<Nn / 4, 256, 0, stream>>>(curp, es, off, invc, comp + l * RR * BB, aggh);
        gemm_k<<<(Nn + 127) / 128, 256, 0, stream>>>(
            curp, aggh, WT + (size_t)l * 5 * 16384, bias_cv + l * HIDd,
            temp, l + 1, nxtp, hidden, (l < LL - 1) ? 1 : 0);
        f16* tmp = nxtp; nxtp = curp; curp = tmp;
    }
    lin2_k<<<(Nn + 63) / 64, 256, 0, stream>>>(hidden, lin2_w, lin2_b, out);
}

// Round 9
// 593.208 us; speedup vs baseline: 7.6226x; 1.0891x over previous
//
#include <hip/hip_runtime.h>

#define Nn   50000
#define Ee   800000
#define INC  256
#define HIDd 128
#define RR   8
#define BB   4
#define LL   3
#define RN   (RR * Nn)   // 400000
#define NCH  391         // ceil(RN / 1024)

typedef _Float16 f16;
typedef _Float16 f16x2 __attribute__((ext_vector_type(2)));
typedef _Float16 f16x8 __attribute__((ext_vector_type(8)));
typedef float    f32x4 __attribute__((ext_vector_type(4)));

static inline size_t align256(size_t x) { return (x + 255) & ~(size_t)255; }

// ---------------- edge bucketing (CSR keyed by r*N + dst) ----------------

__global__ void count_k(const int* __restrict__ ei, const int* __restrict__ et,
                        int* __restrict__ cnt) {
    int e = blockIdx.x * 256 + threadIdx.x;
    if (e < Ee) {
        int d = ei[Ee + e];
        int r = et[e];
        atomicAdd(&cnt[r * Nn + d], 1);
    }
}

__global__ __launch_bounds__(256) void chunksum_k(const int* __restrict__ cnt,
                                                  int* __restrict__ csum) {
    int c = blockIdx.x;
    int t = threadIdx.x;
    int idx4 = c * 256 + t;            // int4 index; RN/4 = 100000
    int s = 0;
    if (idx4 < RN / 4) {
        int4 v = ((const int4*)cnt)[idx4];
        s = v.x + v.y + v.z + v.w;
    }
#pragma unroll
    for (int o = 1; o < 64; o <<= 1) s += __shfl_xor(s, o);
    __shared__ int ws[4];
    if ((t & 63) == 0) ws[t >> 6] = s;
    __syncthreads();
    if (t == 0) csum[c] = ws[0] + ws[1] + ws[2] + ws[3];
}

__global__ __launch_bounds__(512) void chunkscan_k(const int* __restrict__ csum,
                                                   int* __restrict__ cbase,
                                                   int* __restrict__ off) {
    __shared__ int lds[NCH];
    int t = threadIdx.x;
    if (t < NCH) lds[t] = csum[t];
    __syncthreads();
    if (t == 0) {
        int run = 0;
        for (int i = 0; i < NCH; ++i) { int v = lds[i]; lds[i] = run; run += v; }
        off[RN] = run;   // == Ee
    }
    __syncthreads();
    if (t < NCH) cbase[t] = lds[t];
}

__global__ __launch_bounds__(256) void writeoff_k(const int* __restrict__ cnt,
                                                  const int* __restrict__ cbase,
                                                  int* __restrict__ off,
                                                  int* __restrict__ cursor,
                                                  float* __restrict__ invc) {
    int c = blockIdx.x;
    int t = threadIdx.x;
    int idx4 = c * 256 + t;
    bool ok = idx4 < RN / 4;
    int4 v = make_int4(0, 0, 0, 0);
    if (ok) v = ((const int4*)cnt)[idx4];
    int s = v.x + v.y + v.z + v.w;
    int lane = t & 63;
    int incl = s;
#pragma unroll
    for (int o = 1; o < 64; o <<= 1) {
        int u = __shfl_up(incl, o);
        if (lane >= o) incl += u;
    }
    __shared__ int wsum[4];
    if (lane == 63) wsum[t >> 6] = incl;
    __syncthreads();
    int w = t >> 6;
    int wpre = 0;
    if (w > 0) wpre += wsum[0];
    if (w > 1) wpre += wsum[1];
    if (w > 2) wpre += wsum[2];
    int excl = cbase[c] + wpre + incl - s;
    if (ok) {
        int o0 = excl;
        int o1 = o0 + v.x;
        int o2 = o1 + v.y;
        int o3 = o2 + v.z;
        int4 ov = make_int4(o0, o1, o2, o3);
        ((int4*)off)[idx4] = ov;
        ((int4*)cursor)[idx4] = ov;
        float4 iv;
        iv.x = 1.0f / (float)(v.x > 1 ? v.x : 1);
        iv.y = 1.0f / (float)(v.y > 1 ? v.y : 1);
        iv.z = 1.0f / (float)(v.z > 1 ? v.z : 1);
        iv.w = 1.0f / (float)(v.w > 1 ? v.w : 1);
        ((float4*)invc)[idx4] = iv;
    }
}

__global__ void scatter_k(const int* __restrict__ ei, const int* __restrict__ et,
                          int* __restrict__ cursor, int* __restrict__ es) {
    int e = blockIdx.x * 256 + threadIdx.x;
    if (e < Ee) {
        int s = ei[e];
        int d = ei[Ee + e];
        int r = et[e];
        int p = atomicAdd(&cursor[r * Nn + d], 1);
        es[p] = s;
    }
}

// ------- W^T (fp16): chunk 0 = root^T, chunks 1..8 = W_r^T = (sum_b comp[r,b]*bases_b)^T -------

__global__ void makewT_k(const float* __restrict__ bases, const float* __restrict__ comp,
                         const float* __restrict__ root, f16* __restrict__ WT) {
    int idx = blockIdx.x * 256 + threadIdx.x;   // < L*9*16384
    int l = idx / (9 * 16384);
    int rem = idx % (9 * 16384);
    int c = rem >> 14;
    int n = (rem >> 7) & 127;
    int k = rem & 127;
    float v;
    if (c == 0) {
        v = root[l * 16384 + k * 128 + n];
    } else {
        int r = c - 1;
        v = 0.f;
#pragma unroll
        for (int b = 0; b < BB; ++b)
            v += comp[(l * RR + r) * BB + b] * bases[((l * BB + b) << 14) + k * 128 + n];
    }
    WT[idx] = (f16)v;
}

// ---------------- lin1: relu(x @ W1 + b1) * temp0 -> hidden(f32), curh(f16) ----------------

__global__ __launch_bounds__(256) void lin1_k(const float* __restrict__ x,
                                              const float* __restrict__ w1,
                                              const float* __restrict__ b1,
                                              const float* __restrict__ temp,
                                              float* __restrict__ hidden,
                                              f16* __restrict__ curh) {
    __shared__ float Xt[32][130];
    __shared__ float Ws[32][128];
    int t = threadIdx.x;
    int v0 = blockIdx.x * 128;
    int ti = t >> 4, tj = t & 15;
    float acc[8][8];
#pragma unroll
    for (int i = 0; i < 8; ++i)
#pragma unroll
        for (int j = 0; j < 8; ++j) acc[i][j] = 0.f;

    for (int kc = 0; kc < INC; kc += 32) {
        __syncthreads();
        for (int idx = t; idx < 1024; idx += 256) {
            int row = idx >> 3, k4 = (idx & 7) << 2;
            float4 f = make_float4(0.f, 0.f, 0.f, 0.f);
            if (v0 + row < Nn) f = *(const float4*)(x + (size_t)(v0 + row) * INC + kc + k4);
            Xt[k4 + 0][row] = f.x; Xt[k4 + 1][row] = f.y;
            Xt[k4 + 2][row] = f.z; Xt[k4 + 3][row] = f.w;
        }
        for (int idx = t; idx < 1024; idx += 256) {
            int k = idx >> 5, c4 = (idx & 31) << 2;
            *(float4*)&Ws[k][c4] = *(const float4*)(w1 + (size_t)(kc + k) * HIDd + c4);
        }
        __syncthreads();
#pragma unroll 4
        for (int kk = 0; kk < 32; ++kk) {
            float a[8], b[8];
            *(float4*)&a[0] = *(const float4*)&Xt[kk][ti * 8];
            *(float4*)&a[4] = *(const float4*)&Xt[kk][ti * 8 + 4];
            *(float4*)&b[0] = *(const float4*)&Ws[kk][tj * 8];
            *(float4*)&b[4] = *(const float4*)&Ws[kk][tj * 8 + 4];
#pragma unroll
            for (int i = 0; i < 8; ++i)
#pragma unroll
                for (int j = 0; j < 8; ++j) acc[i][j] += a[i] * b[j];
        }
    }
    float t0 = temp[0];
    float bj[8];
#pragma unroll
    for (int j = 0; j < 8; ++j) bj[j] = b1[tj * 8 + j];
#pragma unroll
    for (int i = 0; i < 8; ++i) {
        int v = v0 + ti * 8 + i;
        if (v < Nn) {
            float vals[8];
            f16x8 hv;
#pragma unroll
            for (int j = 0; j < 8; ++j) {
                float val = acc[i][j] + bj[j];
                val = fmaxf(val, 0.f);
                vals[j] = t0 * val;
                hv[j] = (f16)vals[j];
            }
            size_t base = (size_t)v * HIDd + tj * 8;
            *(float4*)(hidden + base)     = *(float4*)&vals[0];
            *(float4*)(hidden + base + 4) = *(float4*)&vals[4];
            *(f16x8*)(curh + base) = hv;
        }
    }
}

// ------- per-(r,dst) mean: 16-lane group per bucket, 4 independent chains/wave -------
// meanb[d][r][k] (f16) = mean over edges of bucket r*Nn+d of curh[src][k]

__global__ __launch_bounds__(256) void meanr_k(const f16* __restrict__ curh,
                                               const int* __restrict__ es,
                                               const int* __restrict__ off,
                                               const float* __restrict__ invc,
                                               f16* __restrict__ meanb) {
    int t = threadIdx.x;
    int g = blockIdx.x * 16 + (t >> 4);   // bucket id = r*Nn + d; RN = 25000*16 exact
    int lane = t & 15;
    int e  = off[g];
    int e1 = off[g + 1];
    float iv = invc[g];
    float acc[8] = {};
    const f16* cb = curh + lane * 8;
    for (; e < e1; ++e) {
        int s = es[e];
        f16x8 v = *(const f16x8*)(cb + (size_t)s * HIDd);
#pragma unroll
        for (int j = 0; j < 8; ++j) acc[j] += (float)v[j];
    }
    int d = g % Nn, r = g / Nn;
    f16x8 o;
#pragma unroll
    for (int j = 0; j < 8; ++j) o[j] = (f16)(acc[j] * iv);
    *(f16x8*)(meanb + (((size_t)d << 3) + r) * HIDd + lane * 8) = o;
}

// ------- dense fp16 MFMA GEMM: C = [curh | mean_0..mean_7] (K=1152) @ WT^T, in-place curh -------

__global__ __launch_bounds__(256, 2) void gemm_k(const f16* __restrict__ curh,
                                                 const f16* __restrict__ meanb,
                                                 const f16* __restrict__ WTl,
                                                 const float* __restrict__ bias,
                                                 const float* __restrict__ temp, int tidx,
                                                 f16* __restrict__ curh_next,
                                                 float* __restrict__ hidden,
                                                 int dorelu) {
    __shared__ f16 Ah[128 * 136];
    __shared__ f16 Bh[128 * 136];
    int t = threadIdx.x;
    int v0 = blockIdx.x * 128;
    int w = t >> 6, lane = t & 63;
    int wr = w >> 1, wc = w & 1;
    int l15 = lane & 15, l4 = lane >> 4;
    int srow = t >> 1, sseg = t & 1;    // staging: row, 64-half segment

    f32x4 acc[4][4] = {};

    for (int c = 0; c < 9; ++c) {
        __syncthreads();
        // stage A (128 rows x 128 halves)
        {
            f16* dst = Ah + srow * 136 + sseg * 64;
            if (v0 + srow < Nn) {
                const f16* src = (c == 0)
                    ? curh + (size_t)(v0 + srow) * HIDd + sseg * 64
                    : meanb + ((size_t)(v0 + srow) * 8 + (c - 1)) * HIDd + sseg * 64;
#pragma unroll
                for (int j = 0; j < 8; ++j)
                    *(f16x8*)(dst + j * 8) = *(const f16x8*)(src + j * 8);
            } else {
                f16x8 z = {};
#pragma unroll
                for (int j = 0; j < 8; ++j)
                    *(f16x8*)(dst + j * 8) = z;
            }
        }
        // stage B^T (128 n-rows x 128 k)
        {
            const f16* src = WTl + (c << 14) + srow * HIDd + sseg * 64;
            f16* dst = Bh + srow * 136 + sseg * 64;
#pragma unroll
            for (int j = 0; j < 8; ++j)
                *(f16x8*)(dst + j * 8) = *(const f16x8*)(src + j * 8);
        }
        __syncthreads();
#pragma unroll
        for (int ks = 0; ks < 4; ++ks) {
            f16x8 af[4], bf[4];
#pragma unroll
            for (int mf = 0; mf < 4; ++mf)
                af[mf] = *(const f16x8*)(Ah + (wr * 64 + mf * 16 + l15) * 136 + ks * 32 + l4 * 8);
#pragma unroll
            for (int nf = 0; nf < 4; ++nf)
                bf[nf] = *(const f16x8*)(Bh + (wc * 64 + nf * 16 + l15) * 136 + ks * 32 + l4 * 8);
#pragma unroll
            for (int mf = 0; mf < 4; ++mf)
#pragma unroll
                for (int nf = 0; nf < 4; ++nf)
                    acc[mf][nf] = __builtin_amdgcn_mfma_f32_16x16x32_f16(af[mf], bf[nf], acc[mf][nf], 0, 0, 0);
        }
    }

    // epilogue: bias, relu, f16 into Ah (reuse), then coalesced writes
    __syncthreads();
    float tl = temp[tidx];
    float bs[4];
#pragma unroll
    for (int nf = 0; nf < 4; ++nf) bs[nf] = bias[wc * 64 + nf * 16 + l15];
#pragma unroll
    for (int mf = 0; mf < 4; ++mf)
#pragma unroll
        for (int nf = 0; nf < 4; ++nf)
#pragma unroll
            for (int j = 0; j < 4; ++j) {
                float val = acc[mf][nf][j] + bs[nf];
                if (dorelu) val = fmaxf(val, 0.f);
                Ah[(wr * 64 + mf * 16 + l4 * 4 + j) * 136 + wc * 64 + nf * 16 + l15] = (f16)val;
            }
    __syncthreads();
    if (v0 + srow < Nn) {
        size_t gb = (size_t)(v0 + srow) * HIDd + sseg * 64;
        const f16* cr = Ah + srow * 136 + sseg * 64;
#pragma unroll
        for (int j = 0; j < 8; ++j)
            *(f16x8*)(curh_next + gb + j * 8) = *(const f16x8*)(cr + j * 8);
        float* hp = hidden + gb;
#pragma unroll
        for (int j = 0; j < 16; ++j) {
            float4 h = *(float4*)(hp + j * 4);
            h.x += tl * (float)cr[j * 4 + 0];
            h.y += tl * (float)cr[j * 4 + 1];
            h.z += tl * (float)cr[j * 4 + 2];
            h.w += tl * (float)cr[j * 4 + 3];
            *(float4*)(hp + j * 4) = h;
        }
    }
}

// ---------------- lin2: hidden @ W2 + b2 -> out [N,2] ----------------

__global__ __launch_bounds__(256) void lin2_k(const float* __restrict__ hidden,
                                              const float* __restrict__ w2,
                                              const float* __restrict__ b2,
                                              float* __restrict__ out) {
    __shared__ float ws[256];
    __shared__ float bs[2];
    int t = threadIdx.x;
    ws[t] = w2[t & 255];
    if (t < 2) bs[t] = b2[t];
    __syncthreads();
    int node = blockIdx.x * 64 + (t >> 2);
    int q = t & 3;
    float a0 = 0.f, a1 = 0.f;
    if (node < Nn) {
        const float* hp = hidden + (size_t)node * HIDd + q * 32;
#pragma unroll
        for (int kk = 0; kk < 32; kk += 4) {
            float4 h = *(const float4*)(hp + kk);
            int kb = (q * 32 + kk) * 2;
            a0 += h.x * ws[kb]     + h.y * ws[kb + 2] + h.z * ws[kb + 4] + h.w * ws[kb + 6];
            a1 += h.x * ws[kb + 1] + h.y * ws[kb + 3] + h.z * ws[kb + 5] + h.w * ws[kb + 7];
        }
    }
    a0 += __shfl_xor(a0, 1); a0 += __shfl_xor(a0, 2);
    a1 += __shfl_xor(a1, 1); a1 += __shfl_xor(a1, 2);
    if (node < Nn && q == 0) {
        out[node * 2 + 0] = a0 + bs[0];
        out[node * 2 + 1] = a1 + bs[1];
    }
}

// ---------------- host ----------------

extern "C" void kernel_launch(void* const* d_in, const int* in_sizes, int n_in,
                              void* d_out, int out_size, void* d_ws, size_t ws_size,
                              hipStream_t stream) {
    (void)in_sizes; (void)n_in; (void)out_size; (void)ws_size;
    const float* x        = (const float*)d_in[0];
    const int*   ei       = (const int*)d_in[1];
    const int*   et       = (const int*)d_in[2];
    const float* lin1_w   = (const float*)d_in[3];
    const float* lin1_b   = (const float*)d_in[4];
    const float* bases    = (const float*)d_in[5];
    const float* comp     = (const float*)d_in[6];
    const float* root     = (const float*)d_in[7];
    const float* bias_cv  = (const float*)d_in[8];
    const float* lin2_w   = (const float*)d_in[9];
    const float* lin2_b   = (const float*)d_in[10];
    const float* temp     = (const float*)d_in[11];
    float* out = (float*)d_out;

    char* w = (char*)d_ws;
    int*   off    = (int*)w;    w += align256((size_t)(RN + 1) * 4);
    int*   cnt    = (int*)w;    w += align256((size_t)RN * 4);
    int*   cursor = (int*)w;    w += align256((size_t)RN * 4);
    float* invc   = (float*)w;  w += align256((size_t)RN * 4);
    int*   csum   = (int*)w;    w += align256((size_t)NCH * 4);
    int*   cbase  = (int*)w;    w += align256((size_t)NCH * 4);
    int*   es     = (int*)w;    w += align256((size_t)Ee * 4);
    f16*   WT     = (f16*)w;    w += align256((size_t)LL * 9 * HIDd * HIDd * 2);
    float* hidden = (float*)w;  w += align256((size_t)Nn * HIDd * 4);
    f16*   curh   = (f16*)w;    w += align256((size_t)Nn * HIDd * 2);
    f16*   meanb  = (f16*)w;    w += align256((size_t)Nn * RR * HIDd * 2);

    hipMemsetAsync(cnt, 0, (size_t)RN * 4, stream);
    count_k<<<(Ee + 255) / 256, 256, 0, stream>>>(ei, et, cnt);
    chunksum_k<<<NCH, 256, 0, stream>>>(cnt, csum);
    chunkscan_k<<<1, 512, 0, stream>>>(csum, cbase, off);
    writeoff_k<<<NCH, 256, 0, stream>>>(cnt, cbase, off, cursor, invc);
    scatter_k<<<(Ee + 255) / 256, 256, 0, stream>>>(ei, et, cursor, es);
    makewT_k<<<(LL * 9 * 16384) / 256, 256, 0, stream>>>(bases, comp, root, WT);
    lin1_k<<<(Nn + 127) / 128, 256, 0, stream>>>(x, lin1_w, lin1_b, temp, hidden, curh);

    for (int l = 0; l < LL; ++l) {
        meanr_k<<<RN / 16, 256, 0, stream>>>(curh, es, off, invc, meanb);
        gemm_k<<<(Nn + 127) / 128, 256, 0, stream>>>(
            curh, meanb, WT + (size_t)l * 9 * 16384, bias_cv + l * HIDd,
            temp, l + 1, curh, hidden, (l < LL - 1) ? 1 : 0);
    }
    lin2_k<<<(Nn + 63) / 64, 256, 0, stream>>>(hidden, lin2_w, lin2_b, out);
}

// Round 10
// 508.665 us; speedup vs baseline: 8.8895x; 1.1662x over previous
//
#include <hip/hip_runtime.h>

#define Nn   50000
#define Ee   800000
#define INC  256
#define HIDd 128
#define RR   8
#define BB   4
#define LL   3
#define RN   (RR * Nn)   // 400000
#define NCH  391         // ceil(RN / 1024)

typedef _Float16 f16;
typedef _Float16 f16x2 __attribute__((ext_vector_type(2)));
typedef _Float16 f16x4 __attribute__((ext_vector_type(4)));
typedef _Float16 f16x8 __attribute__((ext_vector_type(8)));
typedef float    f32x4 __attribute__((ext_vector_type(4)));

static inline size_t align256(size_t x) { return (x + 255) & ~(size_t)255; }

// ---------------- edge bucketing (CSR keyed by r*N + dst) ----------------

__global__ void count_k(const int* __restrict__ ei, const int* __restrict__ et,
                        int* __restrict__ cnt) {
    int e = blockIdx.x * 256 + threadIdx.x;
    if (e < Ee) {
        int d = ei[Ee + e];
        int r = et[e];
        atomicAdd(&cnt[r * Nn + d], 1);
    }
}

__global__ __launch_bounds__(256) void chunksum_k(const int* __restrict__ cnt,
                                                  int* __restrict__ csum) {
    int c = blockIdx.x;
    int t = threadIdx.x;
    int idx4 = c * 256 + t;            // int4 index; RN/4 = 100000
    int s = 0;
    if (idx4 < RN / 4) {
        int4 v = ((const int4*)cnt)[idx4];
        s = v.x + v.y + v.z + v.w;
    }
#pragma unroll
    for (int o = 1; o < 64; o <<= 1) s += __shfl_xor(s, o);
    __shared__ int ws[4];
    if ((t & 63) == 0) ws[t >> 6] = s;
    __syncthreads();
    if (t == 0) csum[c] = ws[0] + ws[1] + ws[2] + ws[3];
}

__global__ __launch_bounds__(512) void chunkscan_k(const int* __restrict__ csum,
                                                   int* __restrict__ cbase,
                                                   int* __restrict__ off) {
    __shared__ int lds[NCH];
    int t = threadIdx.x;
    if (t < NCH) lds[t] = csum[t];
    __syncthreads();
    if (t == 0) {
        int run = 0;
        for (int i = 0; i < NCH; ++i) { int v = lds[i]; lds[i] = run; run += v; }
        off[RN] = run;   // == Ee
    }
    __syncthreads();
    if (t < NCH) cbase[t] = lds[t];
}

__global__ __launch_bounds__(256) void writeoff_k(const int* __restrict__ cnt,
                                                  const int* __restrict__ cbase,
                                                  int* __restrict__ off,
                                                  int* __restrict__ cursor,
                                                  float* __restrict__ invc) {
    int c = blockIdx.x;
    int t = threadIdx.x;
    int idx4 = c * 256 + t;
    bool ok = idx4 < RN / 4;
    int4 v = make_int4(0, 0, 0, 0);
    if (ok) v = ((const int4*)cnt)[idx4];
    int s = v.x + v.y + v.z + v.w;
    int lane = t & 63;
    int incl = s;
#pragma unroll
    for (int o = 1; o < 64; o <<= 1) {
        int u = __shfl_up(incl, o);
        if (lane >= o) incl += u;
    }
    __shared__ int wsum[4];
    if (lane == 63) wsum[t >> 6] = incl;
    __syncthreads();
    int w = t >> 6;
    int wpre = 0;
    if (w > 0) wpre += wsum[0];
    if (w > 1) wpre += wsum[1];
    if (w > 2) wpre += wsum[2];
    int excl = cbase[c] + wpre + incl - s;
    if (ok) {
        int o0 = excl;
        int o1 = o0 + v.x;
        int o2 = o1 + v.y;
        int o3 = o2 + v.z;
        int4 ov = make_int4(o0, o1, o2, o3);
        ((int4*)off)[idx4] = ov;
        ((int4*)cursor)[idx4] = ov;
        float4 iv;
        iv.x = 1.0f / (float)(v.x > 1 ? v.x : 1);
        iv.y = 1.0f / (float)(v.y > 1 ? v.y : 1);
        iv.z = 1.0f / (float)(v.z > 1 ? v.z : 1);
        iv.w = 1.0f / (float)(v.w > 1 ? v.w : 1);
        ((float4*)invc)[idx4] = iv;
    }
}

__global__ void scatter_k(const int* __restrict__ ei, const int* __restrict__ et,
                          int* __restrict__ cursor, int* __restrict__ es) {
    int e = blockIdx.x * 256 + threadIdx.x;
    if (e < Ee) {
        int s = ei[e];
        int d = ei[Ee + e];
        int r = et[e];
        int p = atomicAdd(&cursor[r * Nn + d], 1);
        es[p] = s;
    }
}

// ------- W^T (fp16): chunk 0 = root^T, chunks 1..4 = bases_b^T, per layer -------

__global__ void makewT_k(const float* __restrict__ bases, const float* __restrict__ root,
                         f16* __restrict__ WT) {
    int idx = blockIdx.x * 256 + threadIdx.x;   // < L*5*16384
    int l = idx / (5 * 16384);
    int rem = idx % (5 * 16384);
    int c = rem >> 14;
    int n = (rem >> 7) & 127;
    int k = rem & 127;
    float v = (c == 0) ? root[l * 16384 + k * 128 + n]
                       : bases[((l * BB + (c - 1)) << 14) + k * 128 + n];
    WT[idx] = (f16)v;
}

// ------- x (fp32) -> xh (fp16) -------

__global__ void castx_k(const float* __restrict__ x, f16* __restrict__ xh) {
    int i = blockIdx.x * 256 + threadIdx.x;   // ×4 elems; Nn*INC/4 = 3.2M exact
    float4 v = ((const float4*)x)[i];
    f16x4 o;
    o[0] = (f16)v.x; o[1] = (f16)v.y; o[2] = (f16)v.z; o[3] = (f16)v.w;
    *(f16x4*)(xh + (size_t)i * 4) = o;
}

// ------- w1 (256x128 fp32) -> w1hT (128n x 256k fp16) -------

__global__ void makew1T_k(const float* __restrict__ w1, f16* __restrict__ w1hT) {
    int idx = blockIdx.x * 256 + threadIdx.x;   // < 32768
    int n = idx >> 8, k = idx & 255;
    w1hT[idx] = (f16)w1[k * 128 + n];
}

// ---------------- lin1 via MFMA: relu(xh @ w1hT^T + b1)*temp0 -> hidden(f32), curh(f16) ----------------

__global__ __launch_bounds__(256, 2) void lin1m_k(const f16* __restrict__ xh,
                                                  const f16* __restrict__ w1hT,
                                                  const float* __restrict__ b1,
                                                  const float* __restrict__ temp,
                                                  float* __restrict__ hidden,
                                                  f16* __restrict__ curh) {
    __shared__ f16 Ah[128 * 136];
    __shared__ f16 Bh[128 * 136];
    int t = threadIdx.x;
    int v0 = blockIdx.x * 128;
    int w = t >> 6, lane = t & 63;
    int wr = w >> 1, wc = w & 1;
    int l15 = lane & 15, l4 = lane >> 4;
    int srow = t >> 1, sseg = t & 1;

    f32x4 acc[4][4] = {};

    for (int c = 0; c < 2; ++c) {
        __syncthreads();
        {
            f16* dst = Ah + srow * 136 + sseg * 64;
            if (v0 + srow < Nn) {
                const f16* src = xh + (size_t)(v0 + srow) * INC + c * 128 + sseg * 64;
#pragma unroll
                for (int j = 0; j < 8; ++j)
                    *(f16x8*)(dst + j * 8) = *(const f16x8*)(src + j * 8);
            } else {
                f16x8 z = {};
#pragma unroll
                for (int j = 0; j < 8; ++j)
                    *(f16x8*)(dst + j * 8) = z;
            }
        }
        {
            const f16* src = w1hT + srow * 256 + c * 128 + sseg * 64;
            f16* dst = Bh + srow * 136 + sseg * 64;
#pragma unroll
            for (int j = 0; j < 8; ++j)
                *(f16x8*)(dst + j * 8) = *(const f16x8*)(src + j * 8);
        }
        __syncthreads();
#pragma unroll
        for (int ks = 0; ks < 4; ++ks) {
            f16x8 af[4], bf[4];
#pragma unroll
            for (int mf = 0; mf < 4; ++mf)
                af[mf] = *(const f16x8*)(Ah + (wr * 64 + mf * 16 + l15) * 136 + ks * 32 + l4 * 8);
#pragma unroll
            for (int nf = 0; nf < 4; ++nf)
                bf[nf] = *(const f16x8*)(Bh + (wc * 64 + nf * 16 + l15) * 136 + ks * 32 + l4 * 8);
#pragma unroll
            for (int mf = 0; mf < 4; ++mf)
#pragma unroll
                for (int nf = 0; nf < 4; ++nf)
                    acc[mf][nf] = __builtin_amdgcn_mfma_f32_16x16x32_f16(af[mf], bf[nf], acc[mf][nf], 0, 0, 0);
        }
    }

    __syncthreads();
    float t0 = temp[0];
    float bs[4];
#pragma unroll
    for (int nf = 0; nf < 4; ++nf) bs[nf] = b1[wc * 64 + nf * 16 + l15];
#pragma unroll
    for (int mf = 0; mf < 4; ++mf)
#pragma unroll
        for (int nf = 0; nf < 4; ++nf)
#pragma unroll
            for (int j = 0; j < 4; ++j) {
                float val = fmaxf(acc[mf][nf][j] + bs[nf], 0.f) * t0;
                Ah[(wr * 64 + mf * 16 + l4 * 4 + j) * 136 + wc * 64 + nf * 16 + l15] = (f16)val;
            }
    __syncthreads();
    if (v0 + srow < Nn) {
        size_t gb = (size_t)(v0 + srow) * HIDd + sseg * 64;
        const f16* cr = Ah + srow * 136 + sseg * 64;
#pragma unroll
        for (int j = 0; j < 8; ++j)
            *(f16x8*)(curh + gb + j * 8) = *(const f16x8*)(cr + j * 8);
        float* hp = hidden + gb;
#pragma unroll
        for (int j = 0; j < 16; ++j) {
            float4 h;
            h.x = (float)cr[j * 4 + 0];
            h.y = (float)cr[j * 4 + 1];
            h.z = (float)cr[j * 4 + 2];
            h.w = (float)cr[j * 4 + 3];
            *(float4*)(hp + j * 4) = h;
        }
    }
}

// ------- basis aggregation: block = 2 dst; 8 x 16-lane groups gather per-(r,dst);
//         LDS cross-r reduce with comp -> aggb[d][b][128] (f16), b=0..3 -------

__global__ __launch_bounds__(256) void meanr_k(const f16* __restrict__ curh,
                                               const int* __restrict__ es,
                                               const int* __restrict__ off,
                                               const float* __restrict__ invc,
                                               const float* __restrict__ comp_l,
                                               f16* __restrict__ aggb) {
    __shared__ float ms[2][8][128];
    int t = threadIdx.x;
    int sub = t >> 7;
    int r = (t >> 4) & 7;
    int lane = t & 15;
    int d = blockIdx.x * 2 + sub;
    int g = r * Nn + d;
    int e0 = off[g], e1 = off[g + 1];
    float iv = invc[g];
    float acc[8] = {};
    const f16* cb = curh + lane * 8;
    int e = e0;
    for (; e + 4 <= e1; e += 4) {
        int s0 = es[e], s1 = es[e + 1], s2 = es[e + 2], s3 = es[e + 3];
        f16x8 v0 = *(const f16x8*)(cb + (size_t)s0 * HIDd);
        f16x8 v1 = *(const f16x8*)(cb + (size_t)s1 * HIDd);
        f16x8 v2 = *(const f16x8*)(cb + (size_t)s2 * HIDd);
        f16x8 v3 = *(const f16x8*)(cb + (size_t)s3 * HIDd);
#pragma unroll
        for (int j = 0; j < 8; ++j)
            acc[j] += (float)v0[j] + (float)v1[j] + (float)v2[j] + (float)v3[j];
    }
    for (; e < e1; ++e) {
        int s = es[e];
        f16x8 v = *(const f16x8*)(cb + (size_t)s * HIDd);
#pragma unroll
        for (int j = 0; j < 8; ++j) acc[j] += (float)v[j];
    }
    float4 p0, p1;
    p0.x = acc[0] * iv; p0.y = acc[1] * iv; p0.z = acc[2] * iv; p0.w = acc[3] * iv;
    p1.x = acc[4] * iv; p1.y = acc[5] * iv; p1.z = acc[6] * iv; p1.w = acc[7] * iv;
    *(float4*)&ms[sub][r][lane * 8]     = p0;
    *(float4*)&ms[sub][r][lane * 8 + 4] = p1;
    __syncthreads();
    // combine: thread (sub, k) computes 4 basis outputs for dst d
    int k = t & 127;
    float m[8];
#pragma unroll
    for (int rr = 0; rr < 8; ++rr) m[rr] = ms[sub][rr][k];
    f16* op = aggb + ((size_t)d * 4) * HIDd + k;
#pragma unroll
    for (int b = 0; b < 4; ++b) {
        float o = 0.f;
#pragma unroll
        for (int rr = 0; rr < 8; ++rr) o += comp_l[rr * 4 + b] * m[rr];
        op[b * HIDd] = (f16)o;
    }
}

// ------- dense fp16 MFMA GEMM: C = [curh | aggb0..3] (K=640) @ WT^T, in-place curh -------

__global__ __launch_bounds__(256, 2) void gemm_k(const f16* __restrict__ curh,
                                                 const f16* __restrict__ aggb,
                                                 const f16* __restrict__ WTl,
                                                 const float* __restrict__ bias,
                                                 const float* __restrict__ temp, int tidx,
                                                 f16* __restrict__ curh_next,
                                                 float* __restrict__ hidden,
                                                 int dorelu) {
    __shared__ f16 Ah[128 * 136];
    __shared__ f16 Bh[128 * 136];
    int t = threadIdx.x;
    int v0 = blockIdx.x * 128;
    int w = t >> 6, lane = t & 63;
    int wr = w >> 1, wc = w & 1;
    int l15 = lane & 15, l4 = lane >> 4;
    int srow = t >> 1, sseg = t & 1;

    f32x4 acc[4][4] = {};

    for (int c = 0; c < 5; ++c) {
        __syncthreads();
        {
            f16* dst = Ah + srow * 136 + sseg * 64;
            if (v0 + srow < Nn) {
                const f16* src = (c == 0)
                    ? curh + (size_t)(v0 + srow) * HIDd + sseg * 64
                    : aggb + ((size_t)(v0 + srow) * 4 + (c - 1)) * HIDd + sseg * 64;
#pragma unroll
                for (int j = 0; j < 8; ++j)
                    *(f16x8*)(dst + j * 8) = *(const f16x8*)(src + j * 8);
            } else {
                f16x8 z = {};
#pragma unroll
                for (int j = 0; j < 8; ++j)
                    *(f16x8*)(dst + j * 8) = z;
            }
        }
        {
            const f16* src = WTl + (c << 14) + srow * HIDd + sseg * 64;
            f16* dst = Bh + srow * 136 + sseg * 64;
#pragma unroll
            for (int j = 0; j < 8; ++j)
                *(f16x8*)(dst + j * 8) = *(const f16x8*)(src + j * 8);
        }
        __syncthreads();
#pragma unroll
        for (int ks = 0; ks < 4; ++ks) {
            f16x8 af[4], bf[4];
#pragma unroll
            for (int mf = 0; mf < 4; ++mf)
                af[mf] = *(const f16x8*)(Ah + (wr * 64 + mf * 16 + l15) * 136 + ks * 32 + l4 * 8);
#pragma unroll
            for (int nf = 0; nf < 4; ++nf)
                bf[nf] = *(const f16x8*)(Bh + (wc * 64 + nf * 16 + l15) * 136 + ks * 32 + l4 * 8);
#pragma unroll
            for (int mf = 0; mf < 4; ++mf)
#pragma unroll
                for (int nf = 0; nf < 4; ++nf)
                    acc[mf][nf] = __builtin_amdgcn_mfma_f32_16x16x32_f16(af[mf], bf[nf], acc[mf][nf], 0, 0, 0);
        }
    }

    __syncthreads();
    float tl = temp[tidx];
    float bs[4];
#pragma unroll
    for (int nf = 0; nf < 4; ++nf) bs[nf] = bias[wc * 64 + nf * 16 + l15];
#pragma unroll
    for (int mf = 0; mf < 4; ++mf)
#pragma unroll
        for (int nf = 0; nf < 4; ++nf)
#pragma unroll
            for (int j = 0; j < 4; ++j) {
                float val = acc[mf][nf][j] + bs[nf];
                if (dorelu) val = fmaxf(val, 0.f);
                Ah[(wr * 64 + mf * 16 + l4 * 4 + j) * 136 + wc * 64 + nf * 16 + l15] = (f16)val;
            }
    __syncthreads();
    if (v0 + srow < Nn) {
        size_t gb = (size_t)(v0 + srow) * HIDd + sseg * 64;
        const f16* cr = Ah + srow * 136 + sseg * 64;
#pragma unroll
        for (int j = 0; j < 8; ++j)
            *(f16x8*)(curh_next + gb + j * 8) = *(const f16x8*)(cr + j * 8);
        float* hp = hidden + gb;
#pragma unroll
        for (int j = 0; j < 16; ++j) {
            float4 h = *(float4*)(hp + j * 4);
            h.x += tl * (float)cr[j * 4 + 0];
            h.y += tl * (float)cr[j * 4 + 1];
            h.z += tl * (float)cr[j * 4 + 2];
            h.w += tl * (float)cr[j * 4 + 3];
            *(float4*)(hp + j * 4) = h;
        }
    }
}

// ---------------- lin2: hidden @ W2 + b2 -> out [N,2] ----------------

__global__ __launch_bounds__(256) void lin2_k(const float* __restrict__ hidden,
                                              const float* __restrict__ w2,
                                              const float* __restrict__ b2,
                                              float* __restrict__ out) {
    __shared__ float ws[256];
    __shared__ float bs[2];
    int t = threadIdx.x;
    ws[t] = w2[t & 255];
    if (t < 2) bs[t] = b2[t];
    __syncthreads();
    int node = blockIdx.x * 64 + (t >> 2);
    int q = t & 3;
    float a0 = 0.f, a1 = 0.f;
    if (node < Nn) {
        const float* hp = hidden + (size_t)node * HIDd + q * 32;
#pragma unroll
        for (int kk = 0; kk < 32; kk += 4) {
            float4 h = *(const float4*)(hp + kk);
            int kb = (q * 32 + kk) * 2;
            a0 += h.x * ws[kb]     + h.y * ws[kb + 2] + h.z * ws[kb + 4] + h.w * ws[kb + 6];
            a1 += h.x * ws[kb + 1] + h.y * ws[kb + 3] + h.z * ws[kb + 5] + h.w * ws[kb + 7];
        }
    }
    a0 += __shfl_xor(a0, 1); a0 += __shfl_xor(a0, 2);
    a1 += __shfl_xor(a1, 1); a1 += __shfl_xor(a1, 2);
    if (node < Nn && q == 0) {
        out[node * 2 + 0] = a0 + bs[0];
        out[node * 2 + 1] = a1 + bs[1];
    }
}

// ---------------- host ----------------

extern "C" void kernel_launch(void* const* d_in, const int* in_sizes, int n_in,
                              void* d_out, int out_size, void* d_ws, size_t ws_size,
                              hipStream_t stream) {
    (void)in_sizes; (void)n_in; (void)out_size; (void)ws_size;
    const float* x        = (const float*)d_in[0];
    const int*   ei       = (const int*)d_in[1];
    const int*   et       = (const int*)d_in[2];
    const float* lin1_w   = (const float*)d_in[3];
    const float* lin1_b   = (const float*)d_in[4];
    const float* bases    = (const float*)d_in[5];
    const float* comp     = (const float*)d_in[6];
    const float* root     = (const float*)d_in[7];
    const float* bias_cv  = (const float*)d_in[8];
    const float* lin2_w   = (const float*)d_in[9];
    const float* lin2_b   = (const float*)d_in[10];
    const float* temp     = (const float*)d_in[11];
    float* out = (float*)d_out;

    char* w = (char*)d_ws;
    int*   off    = (int*)w;    w += align256((size_t)(RN + 1) * 4);
    int*   cnt    = (int*)w;    w += align256((size_t)RN * 4);
    int*   cursor = (int*)w;    w += align256((size_t)RN * 4);
    float* invc   = (float*)w;  w += align256((size_t)RN * 4);
    int*   csum   = (int*)w;    w += align256((size_t)NCH * 4);
    int*   cbase  = (int*)w;    w += align256((size_t)NCH * 4);
    int*   es     = (int*)w;    w += align256((size_t)Ee * 4);
    f16*   WT     = (f16*)w;    w += align256((size_t)LL * 5 * HIDd * HIDd * 2);
    f16*   w1hT   = (f16*)w;    w += align256((size_t)HIDd * INC * 2);
    f16*   xh     = (f16*)w;    w += align256((size_t)Nn * INC * 2);
    float* hidden = (float*)w;  w += align256((size_t)Nn * HIDd * 4);
    f16*   curh   = (f16*)w;    w += align256((size_t)Nn * HIDd * 2);
    f16*   aggb   = (f16*)w;    w += align256((size_t)Nn * 4 * HIDd * 2);

    hipMemsetAsync(cnt, 0, (size_t)RN * 4, stream);
    count_k<<<(Ee + 255) / 256, 256, 0, stream>>>(ei, et, cnt);
    chunksum_k<<<NCH, 256, 0, stream>>>(cnt, csum);
    chunkscan_k<<<1, 512, 0, stream>>>(csum, cbase, off);
    writeoff_k<<<NCH, 256, 0, stream>>>(cnt, cbase, off, cursor, invc);
    scatter_k<<<(Ee + 255) / 256, 256, 0, stream>>>(ei, et, cursor, es);
    makewT_k<<<(LL * 5 * 16384) / 256, 256, 0, stream>>>(bases, root, WT);
    castx_k<<<(Nn * INC / 4) / 256, 256, 0, stream>>>(x, xh);
    makew1T_k<<<(HIDd * INC) / 256, 256, 0, stream>>>(lin1_w, w1hT);
    lin1m_k<<<(Nn + 127) / 128, 256, 0, stream>>>(xh, w1hT, lin1_b, temp, hidden, curh);

    for (int l = 0; l < LL; ++l) {
        meanr_k<<<Nn / 2, 256, 0, stream>>>(curh, es, off, invc, comp + l * RR * BB, aggb);
        gemm_k<<<(Nn + 127) / 128, 256, 0, stream>>>(
            curh, aggb, WT + (size_t)l * 5 * 16384, bias_cv + l * HIDd,
            temp, l + 1, curh, hidden, (l < LL - 1) ? 1 : 0);
    }
    lin2_k<<<(Nn + 63) / 64, 256, 0, stream>>>(hidden, lin2_w, lin2_b, out);
}

// Round 11
// 459.595 us; speedup vs baseline: 9.8386x; 1.1068x over previous
//
#include <hip/hip_runtime.h>

#define Nn   50000
#define Ee   800000
#define INC  256
#define HIDd 128
#define RR   8
#define BB   4
#define LL   3
#define RN   (RR * Nn)   // 400000
#define NCH  391         // ceil(RN / 1024)

typedef _Float16 f16;
typedef _Float16 f16x2 __attribute__((ext_vector_type(2)));
typedef _Float16 f16x4 __attribute__((ext_vector_type(4)));
typedef _Float16 f16x8 __attribute__((ext_vector_type(8)));
typedef float    f32x4 __attribute__((ext_vector_type(4)));

static inline size_t align256(size_t x) { return (x + 255) & ~(size_t)255; }

// ---------------- edge bucketing (CSR keyed by r*N + dst) ----------------

__global__ void count_k(const int* __restrict__ ei, const int* __restrict__ et,
                        int* __restrict__ cnt) {
    int e = blockIdx.x * 256 + threadIdx.x;
    if (e < Ee) {
        int d = ei[Ee + e];
        int r = et[e];
        atomicAdd(&cnt[r * Nn + d], 1);
    }
}

__global__ __launch_bounds__(256) void chunksum_k(const int* __restrict__ cnt,
                                                  int* __restrict__ csum) {
    int c = blockIdx.x;
    int t = threadIdx.x;
    int idx4 = c * 256 + t;            // int4 index; RN/4 = 100000
    int s = 0;
    if (idx4 < RN / 4) {
        int4 v = ((const int4*)cnt)[idx4];
        s = v.x + v.y + v.z + v.w;
    }
#pragma unroll
    for (int o = 1; o < 64; o <<= 1) s += __shfl_xor(s, o);
    __shared__ int ws[4];
    if ((t & 63) == 0) ws[t >> 6] = s;
    __syncthreads();
    if (t == 0) csum[c] = ws[0] + ws[1] + ws[2] + ws[3];
}

__global__ __launch_bounds__(512) void chunkscan_k(const int* __restrict__ csum,
                                                   int* __restrict__ cbase,
                                                   int* __restrict__ off) {
    __shared__ int lds[NCH];
    int t = threadIdx.x;
    if (t < NCH) lds[t] = csum[t];
    __syncthreads();
    if (t == 0) {
        int run = 0;
        for (int i = 0; i < NCH; ++i) { int v = lds[i]; lds[i] = run; run += v; }
        off[RN] = run;   // == Ee
    }
    __syncthreads();
    if (t < NCH) cbase[t] = lds[t];
}

__global__ __launch_bounds__(256) void writeoff_k(const int* __restrict__ cnt,
                                                  const int* __restrict__ cbase,
                                                  int* __restrict__ off,
                                                  int* __restrict__ cursor,
                                                  float* __restrict__ invc) {
    int c = blockIdx.x;
    int t = threadIdx.x;
    int idx4 = c * 256 + t;
    bool ok = idx4 < RN / 4;
    int4 v = make_int4(0, 0, 0, 0);
    if (ok) v = ((const int4*)cnt)[idx4];
    int s = v.x + v.y + v.z + v.w;
    int lane = t & 63;
    int incl = s;
#pragma unroll
    for (int o = 1; o < 64; o <<= 1) {
        int u = __shfl_up(incl, o);
        if (lane >= o) incl += u;
    }
    __shared__ int wsum[4];
    if (lane == 63) wsum[t >> 6] = incl;
    __syncthreads();
    int w = t >> 6;
    int wpre = 0;
    if (w > 0) wpre += wsum[0];
    if (w > 1) wpre += wsum[1];
    if (w > 2) wpre += wsum[2];
    int excl = cbase[c] + wpre + incl - s;
    if (ok) {
        int o0 = excl;
        int o1 = o0 + v.x;
        int o2 = o1 + v.y;
        int o3 = o2 + v.z;
        int4 ov = make_int4(o0, o1, o2, o3);
        ((int4*)off)[idx4] = ov;
        ((int4*)cursor)[idx4] = ov;
        float4 iv;
        iv.x = 1.0f / (float)(v.x > 1 ? v.x : 1);
        iv.y = 1.0f / (float)(v.y > 1 ? v.y : 1);
        iv.z = 1.0f / (float)(v.z > 1 ? v.z : 1);
        iv.w = 1.0f / (float)(v.w > 1 ? v.w : 1);
        ((float4*)invc)[idx4] = iv;
    }
}

__global__ void scatter_k(const int* __restrict__ ei, const int* __restrict__ et,
                          int* __restrict__ cursor, int* __restrict__ es) {
    int e = blockIdx.x * 256 + threadIdx.x;
    if (e < Ee) {
        int s = ei[e];
        int d = ei[Ee + e];
        int r = et[e];
        int p = atomicAdd(&cursor[r * Nn + d], 1);
        es[p] = s;
    }
}

// ------- W^T (fp16): chunk 0 = root^T, chunks 1..4 = bases_b^T, per layer -------

__global__ void makewT_k(const float* __restrict__ bases, const float* __restrict__ root,
                         f16* __restrict__ WT) {
    int idx = blockIdx.x * 256 + threadIdx.x;   // < L*5*16384
    int l = idx / (5 * 16384);
    int rem = idx % (5 * 16384);
    int c = rem >> 14;
    int n = (rem >> 7) & 127;
    int k = rem & 127;
    float v = (c == 0) ? root[l * 16384 + k * 128 + n]
                       : bases[((l * BB + (c - 1)) << 14) + k * 128 + n];
    WT[idx] = (f16)v;
}

// ------- w1 (256x128 fp32) -> w1hT (128n x 256k fp16) -------

__global__ void makew1T_k(const float* __restrict__ w1, f16* __restrict__ w1hT) {
    int idx = blockIdx.x * 256 + threadIdx.x;   // < 32768
    int n = idx >> 8, k = idx & 255;
    w1hT[idx] = (f16)w1[k * 128 + n];
}

// ---------------- lin1 via MFMA: relu(x @ w1hT^T + b1)*temp0 -> curh(f16);
//                  out = b2 + temp0 * (cur @ W2)  (init of GPR accumulation) ----------------

__global__ __launch_bounds__(256, 2) void lin1m_k(const float* __restrict__ x,
                                                  const f16* __restrict__ w1hT,
                                                  const float* __restrict__ b1,
                                                  const float* __restrict__ temp,
                                                  const float* __restrict__ w2,
                                                  const float* __restrict__ b2,
                                                  f16* __restrict__ curh,
                                                  float* __restrict__ out) {
    __shared__ f16 Ah[128 * 136];
    __shared__ f16 Bh[128 * 136];
    __shared__ float ws2[256];
    __shared__ float bsh[2];
    int t = threadIdx.x;
    int v0 = blockIdx.x * 128;
    int w = t >> 6, lane = t & 63;
    int wr = w >> 1, wc = w & 1;
    int l15 = lane & 15, l4 = lane >> 4;
    int srow = t >> 1, sseg = t & 1;

    ws2[t] = w2[t];
    if (t < 2) bsh[t] = b2[t];

    f32x4 acc[4][4] = {};

    for (int c = 0; c < 2; ++c) {
        __syncthreads();
        {
            f16* dst = Ah + srow * 136 + sseg * 64;
            if (v0 + srow < Nn) {
                const float* src = x + (size_t)(v0 + srow) * INC + c * 128 + sseg * 64;
#pragma unroll
                for (int j = 0; j < 16; ++j) {
                    float4 f = *(const float4*)(src + j * 4);
                    f16x4 o;
                    o[0] = (f16)f.x; o[1] = (f16)f.y; o[2] = (f16)f.z; o[3] = (f16)f.w;
                    *(f16x4*)(dst + j * 4) = o;
                }
            } else {
                f16x8 z = {};
#pragma unroll
                for (int j = 0; j < 8; ++j)
                    *(f16x8*)(dst + j * 8) = z;
            }
        }
        {
            const f16* src = w1hT + srow * 256 + c * 128 + sseg * 64;
            f16* dst = Bh + srow * 136 + sseg * 64;
#pragma unroll
            for (int j = 0; j < 8; ++j)
                *(f16x8*)(dst + j * 8) = *(const f16x8*)(src + j * 8);
        }
        __syncthreads();
#pragma unroll
        for (int ks = 0; ks < 4; ++ks) {
            f16x8 af[4], bf[4];
#pragma unroll
            for (int mf = 0; mf < 4; ++mf)
                af[mf] = *(const f16x8*)(Ah + (wr * 64 + mf * 16 + l15) * 136 + ks * 32 + l4 * 8);
#pragma unroll
            for (int nf = 0; nf < 4; ++nf)
                bf[nf] = *(const f16x8*)(Bh + (wc * 64 + nf * 16 + l15) * 136 + ks * 32 + l4 * 8);
#pragma unroll
            for (int mf = 0; mf < 4; ++mf)
#pragma unroll
                for (int nf = 0; nf < 4; ++nf)
                    acc[mf][nf] = __builtin_amdgcn_mfma_f32_16x16x32_f16(af[mf], bf[nf], acc[mf][nf], 0, 0, 0);
        }
    }

    __syncthreads();
    float t0 = temp[0];
    float bs[4];
#pragma unroll
    for (int nf = 0; nf < 4; ++nf) bs[nf] = b1[wc * 64 + nf * 16 + l15];
#pragma unroll
    for (int mf = 0; mf < 4; ++mf)
#pragma unroll
        for (int nf = 0; nf < 4; ++nf)
#pragma unroll
            for (int j = 0; j < 4; ++j) {
                float val = fmaxf(acc[mf][nf][j] + bs[nf], 0.f) * t0;
                Ah[(wr * 64 + mf * 16 + l4 * 4 + j) * 136 + wc * 64 + nf * 16 + l15] = (f16)val;
            }
    __syncthreads();
    if (v0 + srow < Nn) {
        size_t gb = (size_t)(v0 + srow) * HIDd + sseg * 64;
        const f16* cr = Ah + srow * 136 + sseg * 64;
#pragma unroll
        for (int j = 0; j < 8; ++j)
            *(f16x8*)(curh + gb + j * 8) = *(const f16x8*)(cr + j * 8);
        // W2 projection of this half-row
        float d0 = 0.f, d1 = 0.f;
#pragma unroll
        for (int q = 0; q < 8; ++q) {
            f16x8 cv = *(const f16x8*)(cr + q * 8);
            const float* wp = &ws2[sseg * 128 + q * 16];
#pragma unroll
            for (int j = 0; j < 8; ++j) {
                float c = (float)cv[j];
                d0 += c * wp[j * 2];
                d1 += c * wp[j * 2 + 1];
            }
        }
        d0 += __shfl_xor(d0, 1);
        d1 += __shfl_xor(d1, 1);
        if (sseg == 0) {
            out[(v0 + srow) * 2 + 0] = bsh[0] + d0;
            out[(v0 + srow) * 2 + 1] = bsh[1] + d1;
        }
    } else {
        // keep shfl partners engaged (uniform control: inactive rows write nothing)
        float d0 = 0.f, d1 = 0.f;
        d0 += __shfl_xor(d0, 1);
        d1 += __shfl_xor(d1, 1);
    }
}

// ------- basis aggregation: block = 2 dst; 8 x 16-lane groups gather per-(r,dst);
//         LDS cross-r reduce with comp -> aggb[d][b][128] (f16), b=0..3 -------

__global__ __launch_bounds__(256) void meanr_k(const f16* __restrict__ curh,
                                               const int* __restrict__ es,
                                               const int* __restrict__ off,
                                               const float* __restrict__ invc,
                                               const float* __restrict__ comp_l,
                                               f16* __restrict__ aggb) {
    __shared__ float ms[2][8][128];
    int t = threadIdx.x;
    int sub = t >> 7;
    int r = (t >> 4) & 7;
    int lane = t & 15;
    int d = blockIdx.x * 2 + sub;
    int g = r * Nn + d;
    int e0 = off[g], e1 = off[g + 1];
    float iv = invc[g];
    float acc[8] = {};
    const f16* cb = curh + lane * 8;
    int e = e0;
    for (; e + 4 <= e1; e += 4) {
        int s0 = es[e], s1 = es[e + 1], s2 = es[e + 2], s3 = es[e + 3];
        f16x8 v0 = *(const f16x8*)(cb + (size_t)s0 * HIDd);
        f16x8 v1 = *(const f16x8*)(cb + (size_t)s1 * HIDd);
        f16x8 v2 = *(const f16x8*)(cb + (size_t)s2 * HIDd);
        f16x8 v3 = *(const f16x8*)(cb + (size_t)s3 * HIDd);
#pragma unroll
        for (int j = 0; j < 8; ++j)
            acc[j] += (float)v0[j] + (float)v1[j] + (float)v2[j] + (float)v3[j];
    }
    for (; e < e1; ++e) {
        int s = es[e];
        f16x8 v = *(const f16x8*)(cb + (size_t)s * HIDd);
#pragma unroll
        for (int j = 0; j < 8; ++j) acc[j] += (float)v[j];
    }
    float4 p0, p1;
    p0.x = acc[0] * iv; p0.y = acc[1] * iv; p0.z = acc[2] * iv; p0.w = acc[3] * iv;
    p1.x = acc[4] * iv; p1.y = acc[5] * iv; p1.z = acc[6] * iv; p1.w = acc[7] * iv;
    *(float4*)&ms[sub][r][lane * 8]     = p0;
    *(float4*)&ms[sub][r][lane * 8 + 4] = p1;
    __syncthreads();
    int k = t & 127;
    float m[8];
#pragma unroll
    for (int rr = 0; rr < 8; ++rr) m[rr] = ms[sub][rr][k];
    f16* op = aggb + ((size_t)d * 4) * HIDd + k;
#pragma unroll
    for (int b = 0; b < 4; ++b) {
        float o = 0.f;
#pragma unroll
        for (int rr = 0; rr < 8; ++rr) o += comp_l[rr * 4 + b] * m[rr];
        op[b * HIDd] = (f16)o;
    }
}

// ------- dense fp16 MFMA GEMM: C = [curh | aggb0..3] (K=640) @ WT^T, in-place curh;
//         out += temp[tidx] * (cur @ W2) -------

__global__ __launch_bounds__(256, 2) void gemm_k(const f16* __restrict__ curh,
                                                 const f16* __restrict__ aggb,
                                                 const f16* __restrict__ WTl,
                                                 const float* __restrict__ bias,
                                                 const float* __restrict__ temp, int tidx,
                                                 const float* __restrict__ w2,
                                                 f16* __restrict__ curh_next,
                                                 float* __restrict__ out,
                                                 int dorelu) {
    __shared__ f16 Ah[128 * 136];
    __shared__ f16 Bh[128 * 136];
    __shared__ float ws2[256];
    int t = threadIdx.x;
    int v0 = blockIdx.x * 128;
    int w = t >> 6, lane = t & 63;
    int wr = w >> 1, wc = w & 1;
    int l15 = lane & 15, l4 = lane >> 4;
    int srow = t >> 1, sseg = t & 1;

    ws2[t] = w2[t];

    f32x4 acc[4][4] = {};

    for (int c = 0; c < 5; ++c) {
        __syncthreads();
        {
            f16* dst = Ah + srow * 136 + sseg * 64;
            if (v0 + srow < Nn) {
                const f16* src = (c == 0)
                    ? curh + (size_t)(v0 + srow) * HIDd + sseg * 64
                    : aggb + ((size_t)(v0 + srow) * 4 + (c - 1)) * HIDd + sseg * 64;
#pragma unroll
                for (int j = 0; j < 8; ++j)
                    *(f16x8*)(dst + j * 8) = *(const f16x8*)(src + j * 8);
            } else {
                f16x8 z = {};
#pragma unroll
                for (int j = 0; j < 8; ++j)
                    *(f16x8*)(dst + j * 8) = z;
            }
        }
        {
            const f16* src = WTl + (c << 14) + srow * HIDd + sseg * 64;
            f16* dst = Bh + srow * 136 + sseg * 64;
#pragma unroll
            for (int j = 0; j < 8; ++j)
                *(f16x8*)(dst + j * 8) = *(const f16x8*)(src + j * 8);
        }
        __syncthreads();
#pragma unroll
        for (int ks = 0; ks < 4; ++ks) {
            f16x8 af[4], bf[4];
#pragma unroll
            for (int mf = 0; mf < 4; ++mf)
                af[mf] = *(const f16x8*)(Ah + (wr * 64 + mf * 16 + l15) * 136 + ks * 32 + l4 * 8);
#pragma unroll
            for (int nf = 0; nf < 4; ++nf)
                bf[nf] = *(const f16x8*)(Bh + (wc * 64 + nf * 16 + l15) * 136 + ks * 32 + l4 * 8);
#pragma unroll
            for (int mf = 0; mf < 4; ++mf)
#pragma unroll
                for (int nf = 0; nf < 4; ++nf)
                    acc[mf][nf] = __builtin_amdgcn_mfma_f32_16x16x32_f16(af[mf], bf[nf], acc[mf][nf], 0, 0, 0);
        }
    }

    __syncthreads();
    float tl = temp[tidx];
    float bs[4];
#pragma unroll
    for (int nf = 0; nf < 4; ++nf) bs[nf] = bias[wc * 64 + nf * 16 + l15];
#pragma unroll
    for (int mf = 0; mf < 4; ++mf)
#pragma unroll
        for (int nf = 0; nf < 4; ++nf)
#pragma unroll
            for (int j = 0; j < 4; ++j) {
                float val = acc[mf][nf][j] + bs[nf];
                if (dorelu) val = fmaxf(val, 0.f);
                Ah[(wr * 64 + mf * 16 + l4 * 4 + j) * 136 + wc * 64 + nf * 16 + l15] = (f16)val;
            }
    __syncthreads();
    if (v0 + srow < Nn) {
        size_t gb = (size_t)(v0 + srow) * HIDd + sseg * 64;
        const f16* cr = Ah + srow * 136 + sseg * 64;
#pragma unroll
        for (int j = 0; j < 8; ++j)
            *(f16x8*)(curh_next + gb + j * 8) = *(const f16x8*)(cr + j * 8);
        float d0 = 0.f, d1 = 0.f;
#pragma unroll
        for (int q = 0; q < 8; ++q) {
            f16x8 cv = *(const f16x8*)(cr + q * 8);
            const float* wp = &ws2[sseg * 128 + q * 16];
#pragma unroll
            for (int j = 0; j < 8; ++j) {
                float c = (float)cv[j];
                d0 += c * wp[j * 2];
                d1 += c * wp[j * 2 + 1];
            }
        }
        d0 += __shfl_xor(d0, 1);
        d1 += __shfl_xor(d1, 1);
        if (sseg == 0) {
            out[(v0 + srow) * 2 + 0] += tl * d0;
            out[(v0 + srow) * 2 + 1] += tl * d1;
        }
    } else {
        float d0 = 0.f, d1 = 0.f;
        d0 += __shfl_xor(d0, 1);
        d1 += __shfl_xor(d1, 1);
    }
}

// ---------------- host ----------------

extern "C" void kernel_launch(void* const* d_in, const int* in_sizes, int n_in,
                              void* d_out, int out_size, void* d_ws, size_t ws_size,
                              hipStream_t stream) {
    (void)in_sizes; (void)n_in; (void)out_size; (void)ws_size;
    const float* x        = (const float*)d_in[0];
    const int*   ei       = (const int*)d_in[1];
    const int*   et       = (const int*)d_in[2];
    const float* lin1_w   = (const float*)d_in[3];
    const float* lin1_b   = (const float*)d_in[4];
    const float* bases    = (const float*)d_in[5];
    const float* comp     = (const float*)d_in[6];
    const float* root     = (const float*)d_in[7];
    const float* bias_cv  = (const float*)d_in[8];
    const float* lin2_w   = (const float*)d_in[9];
    const float* lin2_b   = (const float*)d_in[10];
    const float* temp     = (const float*)d_in[11];
    float* out = (float*)d_out;

    char* w = (char*)d_ws;
    int*   off    = (int*)w;    w += align256((size_t)(RN + 1) * 4);
    int*   cnt    = (int*)w;    w += align256((size_t)RN * 4);
    int*   cursor = (int*)w;    w += align256((size_t)RN * 4);
    float* invc   = (float*)w;  w += align256((size_t)RN * 4);
    int*   csum   = (int*)w;    w += align256((size_t)NCH * 4);
    int*   cbase  = (int*)w;    w += align256((size_t)NCH * 4);
    int*   es     = (int*)w;    w += align256((size_t)Ee * 4);
    f16*   WT     = (f16*)w;    w += align256((size_t)LL * 5 * HIDd * HIDd * 2);
    f16*   w1hT   = (f16*)w;    w += align256((size_t)HIDd * INC * 2);
    f16*   curh   = (f16*)w;    w += align256((size_t)Nn * HIDd * 2);
    f16*   aggb   = (f16*)w;    w += align256((size_t)Nn * 4 * HIDd * 2);

    hipMemsetAsync(cnt, 0, (size_t)RN * 4, stream);
    count_k<<<(Ee + 255) / 256, 256, 0, stream>>>(ei, et, cnt);
    chunksum_k<<<NCH, 256, 0, stream>>>(cnt, csum);
    chunkscan_k<<<1, 512, 0, stream>>>(csum, cbase, off);
    writeoff_k<<<NCH, 256, 0, stream>>>(cnt, cbase, off, cursor, invc);
    scatter_k<<<(Ee + 255) / 256, 256, 0, stream>>>(ei, et, cursor, es);
    makewT_k<<<(LL * 5 * 16384) / 256, 256, 0, stream>>>(bases, root, WT);
    makew1T_k<<<(HIDd * INC) / 256, 256, 0, stream>>>(lin1_w, w1hT);
    lin1m_k<<<(Nn + 127) / 128, 256, 0, stream>>>(x, w1hT, lin1_b, temp, lin2_w, lin2_b,
                                                  curh, out);

    for (int l = 0; l < LL; ++l) {
        meanr_k<<<Nn / 2, 256, 0, stream>>>(curh, es, off, invc, comp + l * RR * BB, aggb);
        gemm_k<<<(Nn + 127) / 128, 256, 0, stream>>>(
            curh, aggb, WT + (size_t)l * 5 * 16384, bias_cv + l * HIDd,
            temp, l + 1, lin2_w, curh, out, (l < LL - 1) ? 1 : 0);
    }
}